// Round 5
// baseline (1152.925 us; speedup 1.0000x reference)
//
#include <hip/hip_runtime.h>
#include <stdint.h>

static constexpr int NN = 50000;   // real nodes
static constexpr int NP = 50048;   // padded rows = 391*128
static constexpr int NE = 200000;  // edges before self-loops
static constexpr int NG = 64;      // graphs
#define BN_S 0.99999500003749968f  // 1/sqrt(1+1e-5)

typedef __bf16 bf16x8 __attribute__((ext_vector_type(8)));
typedef float  f32x4  __attribute__((ext_vector_type(4)));
typedef __attribute__((address_space(1))) void* as1p;
typedef __attribute__((address_space(3))) void* as3p;
typedef unsigned short u16;

__device__ __forceinline__ float b2f(u16 u){ union{uint32_t i;float f;}x; x.i=((uint32_t)u)<<16; return x.f; }
__device__ __forceinline__ float lo_f(uint32_t u){ union{uint32_t i;float f;}x; x.i=u<<16; return x.f; }
__device__ __forceinline__ float hi_f(uint32_t u){ union{uint32_t i;float f;}x; x.i=u&0xffff0000u; return x.f; }
__device__ __forceinline__ u16 f2b(float f){
  union{float f;uint32_t i;}x; x.f=f;
  return (u16)((x.i + 0x7fffu + ((x.i>>16)&1u)) >> 16);
}
__device__ __forceinline__ void lds_cp16(const void* g, void* l){
  __builtin_amdgcn_global_load_lds((as1p)g, (as3p)l, 16, 0, 0);
}

// ---------------- dtype detection ----------------
__global__ void k_detect(const uint32_t* __restrict__ win, int* __restrict__ flag){
  const int lane = threadIdx.x;       // 64 threads
  const uint32_t w = win[lane];
  const int e = (w >> 7) & 0xFF;
  const bool band = (e >= 100 && e <= 140) || ((w & 0xFFFFu) == 0u);
  unsigned long long m = __ballot(band);
  if (lane == 0) *flag = (__popcll(m) < 32) ? 1 : 0;   // 1 => inputs are f32
}

// ---------------- small-param conversion to bf16 arena ----------------
struct CvtJobs {
  const void* src[34];
  int n[34];
  int dstoff[34];
};
__global__ __launch_bounds__(256) void k_cvt(CvtJobs jobs, const int* __restrict__ flag,
                                             u16* __restrict__ dst0){
  const int j = blockIdx.x;
  const int n = jobs.n[j];
  u16* dst = dst0 + jobs.dstoff[j];
  if (*flag){
    const float* s = (const float*)jobs.src[j];
    for (int i = threadIdx.x; i < n; i += 256) dst[i] = f2b(s[i]);
  } else {
    const u16* s = (const u16*)jobs.src[j];
    for (int i = threadIdx.x; i < n; i += 256) dst[i] = s[i];
  }
}

// ---------------- prep kernels (dual dtype) ----------------
__global__ void k_pad_x(const void* __restrict__ x, u16* __restrict__ xp, const int* __restrict__ flag){
  int i = blockIdx.x*256 + threadIdx.x;           // over NP*64
  if (i >= NP*64) return;
  int n = i >> 6, k = i & 63;
  u16 v = 0;
  if (n < NN && k < 62)
    v = (*flag) ? f2b(((const float*)x)[n*62 + k]) : ((const u16*)x)[n*62 + k];
  xp[i] = v;
}
__global__ void k_pad_winT(const void* __restrict__ w, u16* __restrict__ wt, const int* __restrict__ flag){
  int i = blockIdx.x*256 + threadIdx.x;           // over 256*64, i = o*64+k
  if (i >= 256*64) return;
  int o = i >> 6, k = i & 63;
  u16 v = 0;
  if (k < 62)
    v = (*flag) ? f2b(((const float*)w)[k*256 + o]) : ((const u16*)w)[k*256 + o];
  wt[i] = v;
}
__global__ void k_transpose(const void* __restrict__ w, u16* __restrict__ wt, int K, int NO,
                            const int* __restrict__ flag){
  int i = blockIdx.x*256 + threadIdx.x;           // i = k*NO + o
  if (i >= K*NO) return;
  int k = i / NO, o = i - k*NO;
  u16 v = (*flag) ? f2b(((const float*)w)[i]) : ((const u16*)w)[i];
  wt[(size_t)o*K + k] = v;
}

// ---------------- CSR build ----------------
__global__ void k_init_counts(int* counts){
  int i = blockIdx.x*256 + threadIdx.x;
  if (i < NN) counts[i] = 1;                       // self-loop
}
__global__ void k_count(const int* __restrict__ eidx, int* counts){
  int e = blockIdx.x*256 + threadIdx.x;
  if (e < NE) atomicAdd(&counts[eidx[NE + e]], 1);
}
__global__ __launch_bounds__(1024) void k_scan(const int* __restrict__ counts,
                                               int* __restrict__ indptr, int* __restrict__ cursor){
  __shared__ int sums[1024];
  const int t = threadIdx.x;
  const int strip = (NN + 1023)/1024;
  int lo = t*strip, hi = lo+strip < NN ? lo+strip : NN;
  int s = 0;
  for (int i=lo;i<hi;i++) s += counts[i];
  sums[t] = s; __syncthreads();
  for (int off=1; off<1024; off<<=1){
    int v = (t>=off) ? sums[t-off] : 0;
    __syncthreads();
    sums[t] += v;
    __syncthreads();
  }
  int base = t ? sums[t-1] : 0;
  for (int i=lo;i<hi;i++){ indptr[i]=base; cursor[i]=base; base += counts[i]; }
  if (t == 1023) indptr[NN] = sums[1023];
}
__global__ void k_fill(const int* __restrict__ eidx, int* cursor, int* __restrict__ srcs){
  int i = blockIdx.x*256 + threadIdx.x;
  if (i >= NE + NN) return;
  int s, d;
  if (i < NE){ s = eidx[i]; d = eidx[NE+i]; }
  else { s = d = i - NE; }
  int p = atomicAdd(&cursor[d], 1);
  srcs[p] = s;
}

// ---------------- MFMA GEMM: C[M,NOUT] = A[M,K] @ B[NOUT,K]^T ----------------
// global_load_lds staging (m97 structure); 1D grid, bm=bid>>BNSH so the
// 2^BNSH blocks sharing one A-tile are dispatch-adjacent (A hits L3/L2).
template<int K, bool EPI, int BNSH>
__global__ __launch_bounds__(256) void k_gemm_bt(const u16* __restrict__ A, const u16* __restrict__ B,
                                                 u16* __restrict__ C, int ldc, const u16* __restrict__ bias){
  __shared__ __align__(16) u16 As[128*64];
  __shared__ __align__(16) u16 Bs[128*64];
  const int tid = threadIdx.x;
  const int lane = tid & 63, wv = tid >> 6;
  const int bid = blockIdx.x;
  const size_t bm = bid >> BNSH, bn = bid & ((1<<BNSH)-1);
  const u16* Ab = A + bm*128*(size_t)K;
  const u16* Bb = B + bn*128*(size_t)K;
  f32x4 acc[4][4] = {};
  const int wm = (wv>>1)*64, wn = (wv&1)*64;
  const int r = lane & 15, kg = lane >> 4;
  const int srow = wv*32 + (lane>>3);              // staging row in tile
  const int scol = (lane&7)*8;                     // staging col (elements)
  for (int kt = 0; kt < K; kt += 64){
    #pragma unroll
    for (int i=0;i<4;i++){
      lds_cp16(Ab + (size_t)(srow + i*8)*K + kt + scol, (char*)As + (wv*4+i)*1024);
      lds_cp16(Bb + (size_t)(srow + i*8)*K + kt + scol, (char*)Bs + (wv*4+i)*1024);
    }
    __syncthreads();
    #pragma unroll
    for (int ks=0; ks<2; ks++){
      bf16x8 a[4], b[4];
      const int ko = ks*32 + kg*8;
      #pragma unroll
      for (int i=0;i<4;i++) a[i] = *(const bf16x8*)(As + (wm + i*16 + r)*64 + ko);
      #pragma unroll
      for (int j=0;j<4;j++) b[j] = *(const bf16x8*)(Bs + (wn + j*16 + r)*64 + ko);
      #pragma unroll
      for (int i=0;i<4;i++)
        #pragma unroll
        for (int j=0;j<4;j++)
          acc[i][j] = __builtin_amdgcn_mfma_f32_16x16x32_bf16(a[i], b[j], acc[i][j], 0, 0, 0);
    }
    __syncthreads();
  }
  const int rg = lane>>4, cl = lane&15;
  #pragma unroll
  for (int i=0;i<4;i++){
    #pragma unroll
    for (int j=0;j<4;j++){
      const int col = (int)bn*128 + wn + j*16 + cl;
      float bv = 0.f;
      if (EPI) bv = b2f(bias[col]);
      #pragma unroll
      for (int rr=0;rr<4;rr++){
        const int row = (int)bm*128 + wm + i*16 + rg*4 + rr;
        float v = acc[i][j][rr];
        if (EPI){ v += bv; v = v>0.f ? v : 0.f; }
        C[(size_t)row*ldc + col] = f2b(v);
      }
    }
  }
}

// ---------------- per-node attention dots ----------------
template<int H>
__global__ __launch_bounds__(256) void k_alpha(const u16* __restrict__ h,
                                               const u16* __restrict__ a_s, const u16* __restrict__ a_d,
                                               float* __restrict__ os, float* __restrict__ od){
  const int n = blockIdx.x*4 + (threadIdx.x>>6);
  if (n >= NN) return;
  const int lane = threadIdx.x & 63;
  const int c0 = lane*16;                          // 16 channels / lane, HC = 1024
  const uint4 hv0 = *(const uint4*)(h + (size_t)n*1024 + c0);
  const uint4 hv1 = *(const uint4*)(h + (size_t)n*1024 + c0 + 8);
  const uint4 sv0 = *(const uint4*)(a_s + c0);
  const uint4 sv1 = *(const uint4*)(a_s + c0 + 8);
  const uint4 dv0 = *(const uint4*)(a_d + c0);
  const uint4 dv1 = *(const uint4*)(a_d + c0 + 8);
  float ss = 0.f, sd = 0.f;
  uint32_t hu[8] = {hv0.x,hv0.y,hv0.z,hv0.w,hv1.x,hv1.y,hv1.z,hv1.w};
  uint32_t su[8] = {sv0.x,sv0.y,sv0.z,sv0.w,sv1.x,sv1.y,sv1.z,sv1.w};
  uint32_t du[8] = {dv0.x,dv0.y,dv0.z,dv0.w,dv1.x,dv1.y,dv1.z,dv1.w};
  #pragma unroll
  for (int q=0;q<8;q++){
    float h0 = lo_f(hu[q]), h1 = hi_f(hu[q]);
    ss += h0*lo_f(su[q]) + h1*hi_f(su[q]);
    sd += h0*lo_f(du[q]) + h1*hi_f(du[q]);
  }
  const int G = 64 / H;
  #pragma unroll
  for (int off=1; off<G; off<<=1){ ss += __shfl_xor(ss, off); sd += __shfl_xor(sd, off); }
  if ((lane & (G-1)) == 0){
    os[n*H + lane/G] = ss;
    od[n*H + lane/G] = sd;
  }
}

// ---------------- per-(node,head) segment softmax -> unnormalized weights ----------------
template<int H>
__global__ __launch_bounds__(256) void k_soft(const float* __restrict__ asb, const float* __restrict__ adb,
                                              const int* __restrict__ indptr, const int* __restrict__ srcs,
                                              float* __restrict__ wbuf, float* __restrict__ invs){
  const int idx = blockIdx.x*256 + threadIdx.x;    // over NN*H
  if (idx >= NN*H) return;
  const int n = idx / H, hh = idx - n*H;
  const float adn = adb[idx];
  const int p0 = indptr[n], p1 = indptr[n+1];
  float m = -1e30f;
  for (int p = p0; p < p1; ++p){
    float t = asb[srcs[p]*H + hh] + adn;
    float v = t > 0.f ? t : 0.2f*t;
    m = fmaxf(m, v);
  }
  float s = 0.f;
  for (int p = p0; p < p1; ++p){
    float t = asb[srcs[p]*H + hh] + adn;
    float v = t > 0.f ? t : 0.2f*t;
    float e = __expf(v - m);
    wbuf[(size_t)p*H + hh] = e;
    s += e;
  }
  invs[idx] = 1.0f/(s + 1e-16f);
}

// ---------------- aggregation + bias + BN + relu (no LDS, no syncs) ----------------
template<int H, int C, bool FINAL>
__global__ __launch_bounds__(256) void k_agg2(const u16* __restrict__ h,
                                              const float* __restrict__ wbuf, const float* __restrict__ invs,
                                              const int* __restrict__ indptr, const int* __restrict__ srcs,
                                              const u16* __restrict__ bias, const u16* __restrict__ gamma,
                                              const u16* __restrict__ beta, u16* __restrict__ out){
  const int n = blockIdx.x;
  const int tid = threadIdx.x;
  constexpr int OUTW = FINAL ? C : H*C;
  if (n >= NN){
    for (int c = tid; c < OUTW; c += 256) out[(size_t)n*OUTW + c] = 0;
    return;
  }
  const int p0 = indptr[n], p1 = indptr[n+1];
  if (!FINAL){
    const int c0 = tid*4;
    const int hd = c0 >> 7;                        // C = 128
    float a0=0.f,a1=0.f,a2=0.f,a3=0.f;
    int p = p0;
    for (; p + 2 <= p1; p += 2){
      const int s0 = srcs[p], s1 = srcs[p+1];
      const float w0 = wbuf[(size_t)p*H + hd];
      const float w1 = wbuf[(size_t)(p+1)*H + hd];
      const ushort4 v0 = *(const ushort4*)(h + (size_t)s0*1024 + c0);
      const ushort4 v1 = *(const ushort4*)(h + (size_t)s1*1024 + c0);
      a0 += w0*b2f(v0.x) + w1*b2f(v1.x);
      a1 += w0*b2f(v0.y) + w1*b2f(v1.y);
      a2 += w0*b2f(v0.z) + w1*b2f(v1.z);
      a3 += w0*b2f(v0.w) + w1*b2f(v1.w);
    }
    if (p < p1){
      const int s0 = srcs[p];
      const float w0 = wbuf[(size_t)p*H + hd];
      const ushort4 v0 = *(const ushort4*)(h + (size_t)s0*1024 + c0);
      a0 += w0*b2f(v0.x); a1 += w0*b2f(v0.y); a2 += w0*b2f(v0.z); a3 += w0*b2f(v0.w);
    }
    const float is = invs[n*H + hd];
    float vv[4] = {a0,a1,a2,a3};
    u16 ov[4];
    #pragma unroll
    for (int i2=0;i2<4;i2++){
      const int c = c0 + i2;
      float v = (vv[i2]*is + b2f(bias[c])) * (b2f(gamma[c])*BN_S) + b2f(beta[c]);
      ov[i2] = f2b(v>0.f ? v : 0.f);
    }
    *(ushort4*)(out + (size_t)n*1024 + c0) = make_ushort4(ov[0],ov[1],ov[2],ov[3]);
  } else {
    // H=4, C=256: one channel per thread, per-head accumulators
    const int c = tid;
    float a0=0.f,a1=0.f,a2=0.f,a3=0.f;
    for (int p = p0; p < p1; ++p){
      const int s = srcs[p];
      const float4 w4 = *(const float4*)(wbuf + (size_t)p*4);
      const u16* hr = h + (size_t)s*1024 + c;
      a0 += w4.x * b2f(hr[0]);
      a1 += w4.y * b2f(hr[256]);
      a2 += w4.z * b2f(hr[512]);
      a3 += w4.w * b2f(hr[768]);
    }
    const float4 is = *(const float4*)(invs + n*4);
    float meanv = 0.25f*(a0*is.x + a1*is.y + a2*is.z + a3*is.w);
    float v = (meanv + b2f(bias[c])) * (b2f(gamma[c])*BN_S) + b2f(beta[c]);
    out[(size_t)n*C + c] = f2b(v>0.f ? v : 0.f);
  }
}

// ---------------- pooling (parallel, atomic segmented) ----------------
__global__ __launch_bounds__(256) void k_pool_init(float* __restrict__ pooled, int* __restrict__ gcnt){
  int i = blockIdx.x*256 + threadIdx.x;
  if (i < NG*768) pooled[i] = 0.f;
  if (i < NG) gcnt[i] = 0;
}
__global__ __launch_bounds__(256) void k_pool1(const u16* __restrict__ x3, const int* __restrict__ batch,
                                               float* __restrict__ pooled, int* __restrict__ gcnt){
  const int n0 = blockIdx.x*64;
  const int n1 = (n0+64 < NN) ? n0+64 : NN;
  if (n0 >= NN) return;
  const int t = threadIdx.x;
  float sum=0.f, mx=0.f;
  int curg = batch[n0];
  int segstart = n0;
  for (int n=n0; n<n1; ++n){
    const int g = batch[n];
    if (g != curg){
      atomicAdd(&pooled[curg*768+512+t], sum);
      atomicMax((unsigned int*)&pooled[curg*768+256+t], __float_as_uint(mx));
      if (t==0) atomicAdd(&gcnt[curg], n-segstart);
      sum=0.f; mx=0.f; curg=g; segstart=n;
    }
    float v = b2f(x3[(size_t)n*256+t]);
    sum += v; mx = fmaxf(mx, v);
  }
  atomicAdd(&pooled[curg*768+512+t], sum);
  atomicMax((unsigned int*)&pooled[curg*768+256+t], __float_as_uint(mx));
  if (t==0) atomicAdd(&gcnt[curg], n1-segstart);
}
__global__ __launch_bounds__(256) void k_pool_fin(float* __restrict__ pooled, const int* __restrict__ gcnt){
  int i = blockIdx.x*256 + threadIdx.x;            // NG*256
  if (i >= NG*256) return;
  int g = i>>8, c = i&255;
  float s = pooled[g*768+512+c];
  int cnt = gcnt[g];
  pooled[g*768+c] = s / (float)(cnt>1?cnt:1);
}

// ---------------- readout MLPs ----------------
__global__ __launch_bounds__(256) void k_gvec(const float* __restrict__ pooled, const u16* __restrict__ Wp,
                                              const u16* __restrict__ bp, float* __restrict__ gbuf){
  const int g = blockIdx.x, t = threadIdx.x;
  __shared__ float ps[768];
  for (int i=t;i<768;i+=256) ps[i] = pooled[g*768+i];
  __syncthreads();
  float acc = b2f(bp[t]);
  for (int k=0;k<768;k++) acc += ps[k]*b2f(Wp[k*256+t]);
  gbuf[g*256+t] = acc>0.f ? acc : 0.f;
}
__global__ __launch_bounds__(128) void k_heads(const float* __restrict__ gbuf,
    const u16* Wv1,const u16* bv1,const u16* Wv2,const u16* bv2,const u16* Wv3,const u16* bv3,
    const u16* Wt1,const u16* bt1,const u16* Wt2,const u16* bt2,const u16* Wt3,const u16* bt3,
    const u16* Wc1,const u16* bc1,const u16* Wc2,const u16* bc2,
    void* __restrict__ outp, const int* __restrict__ flag){
  const int g = blockIdx.x, t = threadIdx.x;
  const int f32o = *flag;
  u16* o16 = (u16*)outp;
  float* o32 = (float*)outp;
  __shared__ float gs[256], h1[128], h2[64];
  gs[t] = gbuf[g*256+t]; gs[t+128] = gbuf[g*256+t+128];
  __syncthreads();
  { float a = b2f(bv1[t]); for (int k=0;k<256;k++) a += gs[k]*b2f(Wv1[k*128+t]); h1[t] = a>0.f?a:0.f; }
  __syncthreads();
  if (t<64){ float a=b2f(bv2[t]); for(int k=0;k<128;k++) a += h1[k]*b2f(Wv2[k*64+t]); h2[t]=a>0.f?a:0.f; }
  __syncthreads();
  if (t<2){ float a=b2f(bv3[t]); for(int k=0;k<64;k++) a += h2[k]*b2f(Wv3[k*2+t]);
            if (f32o) o32[g*2+t]=a; else o16[g*2+t]=f2b(a); }
  __syncthreads();
  { float a = b2f(bt1[t]); for (int k=0;k<256;k++) a += gs[k]*b2f(Wt1[k*128+t]); h1[t] = a>0.f?a:0.f; }
  __syncthreads();
  if (t<64){ float a=b2f(bt2[t]); for(int k=0;k<128;k++) a += h1[k]*b2f(Wt2[k*64+t]); h2[t]=a>0.f?a:0.f; }
  __syncthreads();
  if (t<10){ float a=b2f(bt3[t]); for(int k=0;k<64;k++) a += h2[k]*b2f(Wt3[k*10+t]);
             if (f32o) o32[128 + g*10+t]=a; else o16[128 + g*10+t]=f2b(a); }
  __syncthreads();
  if (t<64){ float a=b2f(bc1[t]); for(int k=0;k<256;k++) a += gs[k]*b2f(Wc1[k*64+t]); h2[t]=a>0.f?a:0.f; }
  __syncthreads();
  if (t==0){
    float a=b2f(bc2[0]);
    for(int k=0;k<64;k++) a += h2[k]*b2f(Wc2[k]);
    float r = 1.f/(1.f+__expf(-a));
    if (f32o) o32[768+g]=r; else o16[768+g]=f2b(r);
  }
}

extern "C" void kernel_launch(void* const* d_in, const int* in_sizes, int n_in,
                              void* d_out, int out_size, void* d_ws, size_t ws_size,
                              hipStream_t stream){
  (void)in_sizes; (void)n_in; (void)out_size; (void)ws_size;
  const int* eidx = (const int*)d_in[1];
  const int* batch= (const int*)d_in[2];

  char* ws = (char*)d_ws;
  size_t off = 0;
  auto alloc = [&](size_t bytes) -> void* {
    void* p = ws + off;
    off += (bytes + 255) & ~(size_t)255;
    return p;
  };
  u16* bufA  = (u16*)alloc((size_t)NP*1024*2);
  u16* bufH  = (u16*)alloc((size_t)NP*1024*2);
  u16* W1t   = (u16*)alloc((size_t)1024*256*2);
  u16* W2t   = (u16*)alloc((size_t)1024*1024*2);
  u16* W3t   = (u16*)alloc((size_t)1024*1024*2);
  u16* WinT  = (u16*)alloc((size_t)256*64*2);
  // union region: Xp (used only before first k_soft) overlays wbuf+invs
  const size_t wbytes = ((size_t)(NE+NN)*8*4 + 255) & ~(size_t)255;
  const size_t ibytes = (size_t)NN*8*4;
  const size_t xbytes = (size_t)NP*64*2;
  char* un = (char*)alloc(wbytes + ibytes > xbytes ? wbytes + ibytes : xbytes);
  u16*   Xp   = (u16*)un;
  float* wbuf = (float*)un;
  float* invs = (float*)(un + wbytes);
  float* asb = (float*)alloc((size_t)NN*8*4);
  float* adb = (float*)alloc((size_t)NN*8*4);
  int* counts= (int*)alloc((size_t)NN*4);
  int* cursor= (int*)alloc((size_t)NN*4);
  int* indptr= (int*)alloc((size_t)(NN+1)*4);
  int* srcs  = (int*)alloc((size_t)(NE+NN)*4);
  float* pooled = (float*)alloc((size_t)NG*768*4);
  float* gbuf   = (float*)alloc((size_t)NG*256*4);
  int* gcnt  = (int*)alloc((size_t)NG*4);
  u16* cvt   = (u16*)alloc((size_t)320*1024*2);
  int* flag  = (int*)alloc(256);

  // conversion jobs for all small params (everything except x, Win, W1, W2, W3)
  CvtJobs jobs; int ji = 0; int cvtoff = 0;
  auto addjob = [&](int idx, int n) -> u16* {
    jobs.src[ji] = d_in[idx]; jobs.n[ji] = n; jobs.dstoff[ji] = cvtoff; ji++;
    u16* r = cvt + cvtoff; cvtoff = (cvtoff + n + 15) & ~15; return r;
  };
  u16* cb_in= addjob(4, 256);
  u16* cas1 = addjob(6, 1024);  u16* cad1 = addjob(7, 1024);
  u16* cb1  = addjob(8, 1024);  u16* cg1  = addjob(9, 1024);  u16* cbe1 = addjob(10, 1024);
  u16* cas2 = addjob(12, 1024); u16* cad2 = addjob(13, 1024);
  u16* cb2  = addjob(14, 1024); u16* cg2  = addjob(15, 1024); u16* cbe2 = addjob(16, 1024);
  u16* cas3 = addjob(18, 1024); u16* cad3 = addjob(19, 1024);
  u16* cb3  = addjob(20, 256);  u16* cg3  = addjob(21, 256);  u16* cbe3 = addjob(22, 256);
  u16* cWp  = addjob(23, 196608); u16* cbp = addjob(24, 256);
  u16* cWv1 = addjob(25, 32768);  u16* cbv1= addjob(26, 128);
  u16* cWv2 = addjob(27, 8192);   u16* cbv2= addjob(28, 64);
  u16* cWv3 = addjob(29, 128);    u16* cbv3= addjob(30, 2);
  u16* cWt1 = addjob(31, 32768);  u16* cbt1= addjob(32, 128);
  u16* cWt2 = addjob(33, 8192);   u16* cbt2= addjob(34, 64);
  u16* cWt3 = addjob(35, 640);    u16* cbt3= addjob(36, 10);
  u16* cWc1 = addjob(37, 16384);  u16* cbc1= addjob(38, 64);
  u16* cWc2 = addjob(39, 64);     u16* cbc2= addjob(40, 1);

  // dtype detection + conversions
  k_detect<<<1, 64, 0, stream>>>((const uint32_t*)d_in[3], flag);
  k_cvt<<<ji, 256, 0, stream>>>(jobs, flag, cvt);
  k_pad_x<<<(NP*64+255)/256, 256, 0, stream>>>(d_in[0], Xp, flag);
  k_pad_winT<<<(256*64+255)/256, 256, 0, stream>>>(d_in[3], WinT, flag);
  k_transpose<<<(256*1024+255)/256, 256, 0, stream>>>(d_in[5], W1t, 256, 1024, flag);
  k_transpose<<<(1024*1024+255)/256, 256, 0, stream>>>(d_in[11], W2t, 1024, 1024, flag);
  k_transpose<<<(1024*1024+255)/256, 256, 0, stream>>>(d_in[17], W3t, 1024, 1024, flag);

  // CSR build
  k_init_counts<<<(NN+255)/256, 256, 0, stream>>>(counts);
  k_count<<<(NE+255)/256, 256, 0, stream>>>(eidx, counts);
  k_scan<<<1, 1024, 0, stream>>>(counts, indptr, cursor);
  k_fill<<<(NE+NN+255)/256, 256, 0, stream>>>(eidx, cursor, srcs);

  // input transform: relu(x @ Win + b_in) -> bufA [NP,256]
  k_gemm_bt<64,true,1><<<dim3((NP/128)*2), 256, 0, stream>>>(Xp, WinT, bufA, 256, cb_in);

  // layer 1 (H=8, C=128)
  k_gemm_bt<256,false,3><<<dim3((NP/128)*8), 256, 0, stream>>>(bufA, W1t, bufH, 1024, nullptr);
  k_alpha<8><<<(NN+3)/4, 256, 0, stream>>>(bufH, cas1, cad1, asb, adb);
  k_soft<8><<<(NN*8+255)/256, 256, 0, stream>>>(asb, adb, indptr, srcs, wbuf, invs);
  k_agg2<8,128,false><<<NP, 256, 0, stream>>>(bufH, wbuf, invs, indptr, srcs, cb1, cg1, cbe1, bufA);

  // layer 2 (H=8, C=128)
  k_gemm_bt<1024,false,3><<<dim3((NP/128)*8), 256, 0, stream>>>(bufA, W2t, bufH, 1024, nullptr);
  k_alpha<8><<<(NN+3)/4, 256, 0, stream>>>(bufH, cas2, cad2, asb, adb);
  k_soft<8><<<(NN*8+255)/256, 256, 0, stream>>>(asb, adb, indptr, srcs, wbuf, invs);
  k_agg2<8,128,false><<<NP, 256, 0, stream>>>(bufH, wbuf, invs, indptr, srcs, cb2, cg2, cbe2, bufA);

  // layer 3 (H=4, C=256, mean over heads)
  k_gemm_bt<1024,false,3><<<dim3((NP/128)*8), 256, 0, stream>>>(bufA, W3t, bufH, 1024, nullptr);
  k_alpha<4><<<(NN+3)/4, 256, 0, stream>>>(bufH, cas3, cad3, asb, adb);
  k_soft<4><<<(NN*4+255)/256, 256, 0, stream>>>(asb, adb, indptr, srcs, wbuf, invs);
  k_agg2<4,256,true><<<NP, 256, 0, stream>>>(bufH, wbuf, invs, indptr, srcs, cb3, cg3, cbe3, bufA);

  // pooling + readout
  k_pool_init<<<(NG*768+255)/256, 256, 0, stream>>>(pooled, gcnt);
  k_pool1<<<(NN+63)/64, 256, 0, stream>>>(bufA, batch, pooled, gcnt);
  k_pool_fin<<<(NG*256+255)/256, 256, 0, stream>>>(pooled, gcnt);
  k_gvec<<<NG, 256, 0, stream>>>(pooled, cWp, cbp, gbuf);
  k_heads<<<NG, 128, 0, stream>>>(gbuf, cWv1,cbv1,cWv2,cbv2,cWv3,cbv3,
                                  cWt1,cbt1,cWt2,cbt2,cWt3,cbt3, cWc1,cbc1,cWc2,cbc2,
                                  d_out, flag);
}

// Round 6
// 1133.995 us; speedup vs baseline: 1.0167x; 1.0167x over previous
//
#include <hip/hip_runtime.h>
#include <stdint.h>

static constexpr int NN = 50000;   // real nodes
static constexpr int NP = 50176;   // padded rows = 196*256 (also /128 = 392)
static constexpr int NE = 200000;  // edges before self-loops
static constexpr int NG = 64;      // graphs
#define BN_S 0.99999500003749968f  // 1/sqrt(1+1e-5)

typedef __bf16 bf16x8 __attribute__((ext_vector_type(8)));
typedef float  f32x4  __attribute__((ext_vector_type(4)));
typedef __attribute__((address_space(1))) void* as1p;
typedef __attribute__((address_space(3))) void* as3p;
typedef unsigned short u16;

__device__ __forceinline__ float b2f(u16 u){ union{uint32_t i;float f;}x; x.i=((uint32_t)u)<<16; return x.f; }
__device__ __forceinline__ float lo_f(uint32_t u){ union{uint32_t i;float f;}x; x.i=u<<16; return x.f; }
__device__ __forceinline__ float hi_f(uint32_t u){ union{uint32_t i;float f;}x; x.i=u&0xffff0000u; return x.f; }
__device__ __forceinline__ u16 f2b(float f){
  union{float f;uint32_t i;}x; x.f=f;
  return (u16)((x.i + 0x7fffu + ((x.i>>16)&1u)) >> 16);
}
__device__ __forceinline__ void lds_cp16(const void* g, void* l){
  __builtin_amdgcn_global_load_lds((as1p)g, (as3p)l, 16, 0, 0);
}

// ---------------- dtype detection ----------------
__global__ void k_detect(const uint32_t* __restrict__ win, int* __restrict__ flag){
  const int lane = threadIdx.x;       // 64 threads
  const uint32_t w = win[lane];
  const int e = (w >> 7) & 0xFF;
  const bool band = (e >= 100 && e <= 140) || ((w & 0xFFFFu) == 0u);
  unsigned long long m = __ballot(band);
  if (lane == 0) *flag = (__popcll(m) < 32) ? 1 : 0;   // 1 => inputs are f32
}

// ---------------- small-param conversion to bf16 arena ----------------
struct CvtJobs {
  const void* src[34];
  int n[34];
  int dstoff[34];
};
__global__ __launch_bounds__(256) void k_cvt(CvtJobs jobs, const int* __restrict__ flag,
                                             u16* __restrict__ dst0){
  const int j = blockIdx.x;
  const int n = jobs.n[j];
  u16* dst = dst0 + jobs.dstoff[j];
  if (*flag){
    const float* s = (const float*)jobs.src[j];
    for (int i = threadIdx.x; i < n; i += 256) dst[i] = f2b(s[i]);
  } else {
    const u16* s = (const u16*)jobs.src[j];
    for (int i = threadIdx.x; i < n; i += 256) dst[i] = s[i];
  }
}

// ---------------- prep kernels (dual dtype) ----------------
__global__ void k_pad_x(const void* __restrict__ x, u16* __restrict__ xp, const int* __restrict__ flag){
  int i = blockIdx.x*256 + threadIdx.x;           // over NP*64
  if (i >= NP*64) return;
  int n = i >> 6, k = i & 63;
  u16 v = 0;
  if (n < NN && k < 62)
    v = (*flag) ? f2b(((const float*)x)[n*62 + k]) : ((const u16*)x)[n*62 + k];
  xp[i] = v;
}
__global__ void k_pad_winT(const void* __restrict__ w, u16* __restrict__ wt, const int* __restrict__ flag){
  int i = blockIdx.x*256 + threadIdx.x;           // over 256*64, i = o*64+k
  if (i >= 256*64) return;
  int o = i >> 6, k = i & 63;
  u16 v = 0;
  if (k < 62)
    v = (*flag) ? f2b(((const float*)w)[k*256 + o]) : ((const u16*)w)[k*256 + o];
  wt[i] = v;
}
__global__ void k_transpose(const void* __restrict__ w, u16* __restrict__ wt, int K, int NO,
                            const int* __restrict__ flag){
  int i = blockIdx.x*256 + threadIdx.x;           // i = k*NO + o
  if (i >= K*NO) return;
  int k = i / NO, o = i - k*NO;
  u16 v = (*flag) ? f2b(((const float*)w)[i]) : ((const u16*)w)[i];
  wt[(size_t)o*K + k] = v;
}

// ---------------- CSR build ----------------
__global__ void k_init_counts(int* counts){
  int i = blockIdx.x*256 + threadIdx.x;
  if (i < NN) counts[i] = 1;                       // self-loop
}
__global__ void k_count(const int* __restrict__ eidx, int* counts){
  int e = blockIdx.x*256 + threadIdx.x;
  if (e < NE) atomicAdd(&counts[eidx[NE + e]], 1);
}
__global__ __launch_bounds__(1024) void k_scan(const int* __restrict__ counts,
                                               int* __restrict__ indptr, int* __restrict__ cursor){
  __shared__ int sums[1024];
  const int t = threadIdx.x;
  const int strip = (NN + 1023)/1024;
  int lo = t*strip, hi = lo+strip < NN ? lo+strip : NN;
  int s = 0;
  for (int i=lo;i<hi;i++) s += counts[i];
  sums[t] = s; __syncthreads();
  for (int off=1; off<1024; off<<=1){
    int v = (t>=off) ? sums[t-off] : 0;
    __syncthreads();
    sums[t] += v;
    __syncthreads();
  }
  int base = t ? sums[t-1] : 0;
  for (int i=lo;i<hi;i++){ indptr[i]=base; cursor[i]=base; base += counts[i]; }
  if (t == 1023) indptr[NN] = sums[1023];
}
__global__ void k_fill(const int* __restrict__ eidx, int* cursor, int* __restrict__ srcs){
  int i = blockIdx.x*256 + threadIdx.x;
  if (i >= NE + NN) return;
  int s, d;
  if (i < NE){ s = eidx[i]; d = eidx[NE+i]; }
  else { s = d = i - NE; }
  int p = atomicAdd(&cursor[d], 1);
  srcs[p] = s;
}

// ---------------- 128-tile MFMA GEMM (kept for the K=64 input transform) ----------------
template<int K, bool EPI, int BNSH>
__global__ __launch_bounds__(256) void k_gemm_bt(const u16* __restrict__ A, const u16* __restrict__ B,
                                                 u16* __restrict__ C, int ldc, const u16* __restrict__ bias){
  __shared__ __align__(16) u16 As[128*64];
  __shared__ __align__(16) u16 Bs[128*64];
  const int tid = threadIdx.x;
  const int lane = tid & 63, wv = tid >> 6;
  const int bid = blockIdx.x;
  const size_t bm = bid >> BNSH, bn = bid & ((1<<BNSH)-1);
  const u16* Ab = A + bm*128*(size_t)K;
  const u16* Bb = B + bn*128*(size_t)K;
  f32x4 acc[4][4] = {};
  const int wm = (wv>>1)*64, wn = (wv&1)*64;
  const int r = lane & 15, kg = lane >> 4;
  const int srow = wv*32 + (lane>>3);
  const int scol = (lane&7)*8;
  for (int kt = 0; kt < K; kt += 64){
    #pragma unroll
    for (int i=0;i<4;i++){
      lds_cp16(Ab + (size_t)(srow + i*8)*K + kt + scol, (char*)As + (wv*4+i)*1024);
      lds_cp16(Bb + (size_t)(srow + i*8)*K + kt + scol, (char*)Bs + (wv*4+i)*1024);
    }
    __syncthreads();
    #pragma unroll
    for (int ks=0; ks<2; ks++){
      bf16x8 a[4], b[4];
      const int ko = ks*32 + kg*8;
      #pragma unroll
      for (int i=0;i<4;i++) a[i] = *(const bf16x8*)(As + (wm + i*16 + r)*64 + ko);
      #pragma unroll
      for (int j=0;j<4;j++) b[j] = *(const bf16x8*)(Bs + (wn + j*16 + r)*64 + ko);
      #pragma unroll
      for (int i=0;i<4;i++)
        #pragma unroll
        for (int j=0;j<4;j++)
          acc[i][j] = __builtin_amdgcn_mfma_f32_16x16x32_bf16(a[i], b[j], acc[i][j], 0, 0, 0);
    }
    __syncthreads();
  }
  const int rg = lane>>4, cl = lane&15;
  #pragma unroll
  for (int i=0;i<4;i++){
    #pragma unroll
    for (int j=0;j<4;j++){
      const int col = (int)bn*128 + wn + j*16 + cl;
      float bv = 0.f;
      if (EPI) bv = b2f(bias[col]);
      #pragma unroll
      for (int rr=0;rr<4;rr++){
        const int row = (int)bm*128 + wm + i*16 + rg*4 + rr;
        float v = acc[i][j][rr];
        if (EPI){ v += bv; v = v>0.f ? v : 0.f; }
        C[(size_t)row*ldc + col] = f2b(v);
      }
    }
  }
}

// ---------------- 256-tile 8-phase MFMA GEMM (T3 interleave + T5 setprio, linear LDS) ----------------
// C[M,N] = A[M,K] @ B[N,K]^T.  512 threads = 8 waves (2 Mx4 N), per-wave 128x64 out.
// LDS: 2 x (A[256][64] | B[256][64]) = 128 KiB double buffer, compile-time offsets.
template<int K, int BNT>
__global__ __launch_bounds__(512, 2) void k_gemm256(const u16* __restrict__ A, const u16* __restrict__ B,
                                                    u16* __restrict__ C, int ldc){
  __shared__ __align__(16) u16 lds[65536];        // 128 KiB
  const int tid = threadIdx.x;
  const int lane = tid & 63, wid = tid >> 6;
  const int wr = wid >> 2, wc = wid & 3;
  const int bm = blockIdx.x / BNT, bn = blockIdx.x % BNT;
  const u16* Ab = A + (size_t)bm*256*K;
  const u16* Bb = B + (size_t)bn*256*K;
  const int r = lane & 15, kg = lane >> 4;
  f32x4 acc[8][4] = {};

  // stage half-tile `which` (0=Ah0,1=Ah1,2=Bh0,3=Bh1) of K-tile T into buffer at u16-offset wro
  auto stage = [&](int which, int T, int wro){
    const u16* src = (which < 2 ? Ab + (size_t)(which*128)*K
                                : Bb + (size_t)((which-2)*128)*K) + (size_t)T*64;
    u16* dst = lds + wro + (which >= 2 ? 16384 : 0) + (which & 1)*8192;
    #pragma unroll
    for (int L = 0; L < 2; L++){
      const int off = L*4096 + tid*8;             // u16 units; lane-linear 16B
      lds_cp16(src + (size_t)(off >> 6)*K + (off & 63), dst + off);
    }
  };

  // one K-tile: 4 phases of {8x ds_read_b128 ; 1 half-tile stage ; barrier ; 16 MFMA ; barrier}
  auto do_tile = [&](int T, int rdo, int wro, bool prefetch){
    const u16* As_ = lds + rdo;
    const u16* Bs_ = lds + rdo + 16384;
    #pragma unroll
    for (int p = 0; p < 4; ++p){
      const int h = p >> 1, ks = p & 1;
      bf16x8 a[4], b[4];
      const u16* ap = As_ + (wr*128 + h*64 + r)*64 + ks*32 + kg*8;
      const u16* bp = Bs_ + (wc*64  +        r)*64 + ks*32 + kg*8;
      #pragma unroll
      for (int m = 0; m < 4; m++) a[m] = *(const bf16x8*)(ap + m*1024);
      #pragma unroll
      for (int n = 0; n < 4; n++) b[n] = *(const bf16x8*)(bp + n*1024);
      if (prefetch) stage(p, T+1, wro);
      __builtin_amdgcn_s_barrier();
      __builtin_amdgcn_s_setprio(1);
      #pragma unroll
      for (int m = 0; m < 4; m++)
        #pragma unroll
        for (int n = 0; n < 4; n++)
          acc[h*4+m][n] = __builtin_amdgcn_mfma_f32_16x16x32_bf16(a[m], b[n], acc[h*4+m][n], 0, 0, 0);
      __builtin_amdgcn_s_setprio(0);
      if (p < 3) __builtin_amdgcn_s_barrier();
      else       __syncthreads();                 // tile boundary: drain vmcnt (next buffer ready)
    }
  };

  constexpr int NT = K/64;                        // even for all instantiations
  stage(0,0,0); stage(1,0,0); stage(2,0,0); stage(3,0,0);
  __syncthreads();
  for (int T = 0; T < NT; T += 2){
    do_tile(T,     0,     32768, true);           // stages T+1 into hi buffer
    do_tile(T+1, 32768,   0,     T+2 < NT);       // stages T+2 into lo buffer
  }

  const int cl = lane & 15, rg = lane >> 4;
  #pragma unroll
  for (int h = 0; h < 2; h++)
    #pragma unroll
    for (int m = 0; m < 4; m++)
      #pragma unroll
      for (int n = 0; n < 4; n++){
        const int col = bn*256 + wc*64 + n*16 + cl;
        #pragma unroll
        for (int rr = 0; rr < 4; rr++){
          const int row = bm*256 + wr*128 + h*64 + m*16 + rg*4 + rr;
          C[(size_t)row*ldc + col] = f2b(acc[h*4+m][n][rr]);
        }
      }
}

// ---------------- per-node attention dots ----------------
template<int H>
__global__ __launch_bounds__(256) void k_alpha(const u16* __restrict__ h,
                                               const u16* __restrict__ a_s, const u16* __restrict__ a_d,
                                               float* __restrict__ os, float* __restrict__ od){
  const int n = blockIdx.x*4 + (threadIdx.x>>6);
  if (n >= NN) return;
  const int lane = threadIdx.x & 63;
  const int c0 = lane*16;
  const uint4 hv0 = *(const uint4*)(h + (size_t)n*1024 + c0);
  const uint4 hv1 = *(const uint4*)(h + (size_t)n*1024 + c0 + 8);
  const uint4 sv0 = *(const uint4*)(a_s + c0);
  const uint4 sv1 = *(const uint4*)(a_s + c0 + 8);
  const uint4 dv0 = *(const uint4*)(a_d + c0);
  const uint4 dv1 = *(const uint4*)(a_d + c0 + 8);
  float ss = 0.f, sd = 0.f;
  uint32_t hu[8] = {hv0.x,hv0.y,hv0.z,hv0.w,hv1.x,hv1.y,hv1.z,hv1.w};
  uint32_t su[8] = {sv0.x,sv0.y,sv0.z,sv0.w,sv1.x,sv1.y,sv1.z,sv1.w};
  uint32_t du[8] = {dv0.x,dv0.y,dv0.z,dv0.w,dv1.x,dv1.y,dv1.z,dv1.w};
  #pragma unroll
  for (int q=0;q<8;q++){
    float h0 = lo_f(hu[q]), h1 = hi_f(hu[q]);
    ss += h0*lo_f(su[q]) + h1*hi_f(su[q]);
    sd += h0*lo_f(du[q]) + h1*hi_f(du[q]);
  }
  const int G = 64 / H;
  #pragma unroll
  for (int off=1; off<G; off<<=1){ ss += __shfl_xor(ss, off); sd += __shfl_xor(sd, off); }
  if ((lane & (G-1)) == 0){
    os[n*H + lane/G] = ss;
    od[n*H + lane/G] = sd;
  }
}

// ---------------- per-(node,head) segment softmax -> unnormalized weights ----------------
template<int H>
__global__ __launch_bounds__(256) void k_soft(const float* __restrict__ asb, const float* __restrict__ adb,
                                              const int* __restrict__ indptr, const int* __restrict__ srcs,
                                              float* __restrict__ wbuf, float* __restrict__ invs){
  const int idx = blockIdx.x*256 + threadIdx.x;
  if (idx >= NN*H) return;
  const int n = idx / H, hh = idx - n*H;
  const float adn = adb[idx];
  const int p0 = indptr[n], p1 = indptr[n+1];
  float m = -1e30f;
  for (int p = p0; p < p1; ++p){
    float t = asb[srcs[p]*H + hh] + adn;
    float v = t > 0.f ? t : 0.2f*t;
    m = fmaxf(m, v);
  }
  float s = 0.f;
  for (int p = p0; p < p1; ++p){
    float t = asb[srcs[p]*H + hh] + adn;
    float v = t > 0.f ? t : 0.2f*t;
    float e = __expf(v - m);
    wbuf[(size_t)p*H + hh] = e;
    s += e;
  }
  invs[idx] = 1.0f/(s + 1e-16f);
}

// ---------------- aggregation + bias + BN + relu (no LDS, no syncs) ----------------
template<int H, int C, bool FINAL>
__global__ __launch_bounds__(256) void k_agg2(const u16* __restrict__ h,
                                              const float* __restrict__ wbuf, const float* __restrict__ invs,
                                              const int* __restrict__ indptr, const int* __restrict__ srcs,
                                              const u16* __restrict__ bias, const u16* __restrict__ gamma,
                                              const u16* __restrict__ beta, u16* __restrict__ out){
  const int n = blockIdx.x;
  const int tid = threadIdx.x;
  constexpr int OUTW = FINAL ? C : H*C;
  if (n >= NN){
    for (int c = tid; c < OUTW; c += 256) out[(size_t)n*OUTW + c] = 0;
    return;
  }
  const int p0 = indptr[n], p1 = indptr[n+1];
  if (!FINAL){
    const int c0 = tid*4;
    const int hd = c0 >> 7;                        // C = 128
    float a0=0.f,a1=0.f,a2=0.f,a3=0.f;
    int p = p0;
    for (; p + 2 <= p1; p += 2){
      const int s0 = srcs[p], s1 = srcs[p+1];
      const float w0 = wbuf[(size_t)p*H + hd];
      const float w1 = wbuf[(size_t)(p+1)*H + hd];
      const ushort4 v0 = *(const ushort4*)(h + (size_t)s0*1024 + c0);
      const ushort4 v1 = *(const ushort4*)(h + (size_t)s1*1024 + c0);
      a0 += w0*b2f(v0.x) + w1*b2f(v1.x);
      a1 += w0*b2f(v0.y) + w1*b2f(v1.y);
      a2 += w0*b2f(v0.z) + w1*b2f(v1.z);
      a3 += w0*b2f(v0.w) + w1*b2f(v1.w);
    }
    if (p < p1){
      const int s0 = srcs[p];
      const float w0 = wbuf[(size_t)p*H + hd];
      const ushort4 v0 = *(const ushort4*)(h + (size_t)s0*1024 + c0);
      a0 += w0*b2f(v0.x); a1 += w0*b2f(v0.y); a2 += w0*b2f(v0.z); a3 += w0*b2f(v0.w);
    }
    const float is = invs[n*H + hd];
    float vv[4] = {a0,a1,a2,a3};
    u16 ov[4];
    #pragma unroll
    for (int i2=0;i2<4;i2++){
      const int c = c0 + i2;
      float v = (vv[i2]*is + b2f(bias[c])) * (b2f(gamma[c])*BN_S) + b2f(beta[c]);
      ov[i2] = f2b(v>0.f ? v : 0.f);
    }
    *(ushort4*)(out + (size_t)n*1024 + c0) = make_ushort4(ov[0],ov[1],ov[2],ov[3]);
  } else {
    const int c = tid;
    float a0=0.f,a1=0.f,a2=0.f,a3=0.f;
    for (int p = p0; p < p1; ++p){
      const int s = srcs[p];
      const float4 w4 = *(const float4*)(wbuf + (size_t)p*4);
      const u16* hr = h + (size_t)s*1024 + c;
      a0 += w4.x * b2f(hr[0]);
      a1 += w4.y * b2f(hr[256]);
      a2 += w4.z * b2f(hr[512]);
      a3 += w4.w * b2f(hr[768]);
    }
    const float4 is = *(const float4*)(invs + n*4);
    float meanv = 0.25f*(a0*is.x + a1*is.y + a2*is.z + a3*is.w);
    float v = (meanv + b2f(bias[c])) * (b2f(gamma[c])*BN_S) + b2f(beta[c]);
    out[(size_t)n*C + c] = f2b(v>0.f ? v : 0.f);
  }
}

// ---------------- pooling (parallel, atomic segmented) ----------------
__global__ __launch_bounds__(256) void k_pool_init(float* __restrict__ pooled, int* __restrict__ gcnt){
  int i = blockIdx.x*256 + threadIdx.x;
  if (i < NG*768) pooled[i] = 0.f;
  if (i < NG) gcnt[i] = 0;
}
__global__ __launch_bounds__(256) void k_pool1(const u16* __restrict__ x3, const int* __restrict__ batch,
                                               float* __restrict__ pooled, int* __restrict__ gcnt){
  const int n0 = blockIdx.x*64;
  const int n1 = (n0+64 < NN) ? n0+64 : NN;
  if (n0 >= NN) return;
  const int t = threadIdx.x;
  float sum=0.f, mx=0.f;
  int curg = batch[n0];
  int segstart = n0;
  for (int n=n0; n<n1; ++n){
    const int g = batch[n];
    if (g != curg){
      atomicAdd(&pooled[curg*768+512+t], sum);
      atomicMax((unsigned int*)&pooled[curg*768+256+t], __float_as_uint(mx));
      if (t==0) atomicAdd(&gcnt[curg], n-segstart);
      sum=0.f; mx=0.f; curg=g; segstart=n;
    }
    float v = b2f(x3[(size_t)n*256+t]);
    sum += v; mx = fmaxf(mx, v);
  }
  atomicAdd(&pooled[curg*768+512+t], sum);
  atomicMax((unsigned int*)&pooled[curg*768+256+t], __float_as_uint(mx));
  if (t==0) atomicAdd(&gcnt[curg], n1-segstart);
}
__global__ __launch_bounds__(256) void k_pool_fin(float* __restrict__ pooled, const int* __restrict__ gcnt){
  int i = blockIdx.x*256 + threadIdx.x;
  if (i >= NG*256) return;
  int g = i>>8, c = i&255;
  float s = pooled[g*768+512+c];
  int cnt = gcnt[g];
  pooled[g*768+c] = s / (float)(cnt>1?cnt:1);
}

// ---------------- readout MLPs ----------------
__global__ __launch_bounds__(256) void k_gvec(const float* __restrict__ pooled, const u16* __restrict__ Wp,
                                              const u16* __restrict__ bp, float* __restrict__ gbuf){
  const int g = blockIdx.x, t = threadIdx.x;
  __shared__ float ps[768];
  for (int i=t;i<768;i+=256) ps[i] = pooled[g*768+i];
  __syncthreads();
  float acc = b2f(bp[t]);
  for (int k=0;k<768;k++) acc += ps[k]*b2f(Wp[k*256+t]);
  gbuf[g*256+t] = acc>0.f ? acc : 0.f;
}
__global__ __launch_bounds__(128) void k_heads(const float* __restrict__ gbuf,
    const u16* Wv1,const u16* bv1,const u16* Wv2,const u16* bv2,const u16* Wv3,const u16* bv3,
    const u16* Wt1,const u16* bt1,const u16* Wt2,const u16* bt2,const u16* Wt3,const u16* bt3,
    const u16* Wc1,const u16* bc1,const u16* Wc2,const u16* bc2,
    void* __restrict__ outp, const int* __restrict__ flag){
  const int g = blockIdx.x, t = threadIdx.x;
  const int f32o = *flag;
  u16* o16 = (u16*)outp;
  float* o32 = (float*)outp;
  __shared__ float gs[256], h1[128], h2[64];
  gs[t] = gbuf[g*256+t]; gs[t+128] = gbuf[g*256+t+128];
  __syncthreads();
  { float a = b2f(bv1[t]); for (int k=0;k<256;k++) a += gs[k]*b2f(Wv1[k*128+t]); h1[t] = a>0.f?a:0.f; }
  __syncthreads();
  if (t<64){ float a=b2f(bv2[t]); for(int k=0;k<128;k++) a += h1[k]*b2f(Wv2[k*64+t]); h2[t]=a>0.f?a:0.f; }
  __syncthreads();
  if (t<2){ float a=b2f(bv3[t]); for(int k=0;k<64;k++) a += h2[k]*b2f(Wv3[k*2+t]);
            if (f32o) o32[g*2+t]=a; else o16[g*2+t]=f2b(a); }
  __syncthreads();
  { float a = b2f(bt1[t]); for (int k=0;k<256;k++) a += gs[k]*b2f(Wt1[k*128+t]); h1[t] = a>0.f?a:0.f; }
  __syncthreads();
  if (t<64){ float a=b2f(bt2[t]); for(int k=0;k<128;k++) a += h1[k]*b2f(Wt2[k*64+t]); h2[t]=a>0.f?a:0.f; }
  __syncthreads();
  if (t<10){ float a=b2f(bt3[t]); for(int k=0;k<64;k++) a += h2[k]*b2f(Wt3[k*10+t]);
             if (f32o) o32[128 + g*10+t]=a; else o16[128 + g*10+t]=f2b(a); }
  __syncthreads();
  if (t<64){ float a=b2f(bc1[t]); for(int k=0;k<256;k++) a += gs[k]*b2f(Wc1[k*64+t]); h2[t]=a>0.f?a:0.f; }
  __syncthreads();
  if (t==0){
    float a=b2f(bc2[0]);
    for(int k=0;k<64;k++) a += h2[k]*b2f(Wc2[k]);
    float r = 1.f/(1.f+__expf(-a));
    if (f32o) o32[768+g]=r; else o16[768+g]=f2b(r);
  }
}

extern "C" void kernel_launch(void* const* d_in, const int* in_sizes, int n_in,
                              void* d_out, int out_size, void* d_ws, size_t ws_size,
                              hipStream_t stream){
  (void)in_sizes; (void)n_in; (void)out_size; (void)ws_size;
  const int* eidx = (const int*)d_in[1];
  const int* batch= (const int*)d_in[2];

  char* ws = (char*)d_ws;
  size_t off = 0;
  auto alloc = [&](size_t bytes) -> void* {
    void* p = ws + off;
    off += (bytes + 255) & ~(size_t)255;
    return p;
  };
  u16* bufA  = (u16*)alloc((size_t)NP*1024*2);
  u16* bufH  = (u16*)alloc((size_t)NP*1024*2);
  u16* W1t   = (u16*)alloc((size_t)1024*256*2);
  u16* W2t   = (u16*)alloc((size_t)1024*1024*2);
  u16* W3t   = (u16*)alloc((size_t)1024*1024*2);
  u16* WinT  = (u16*)alloc((size_t)256*64*2);
  // union region: Xp (used only before first k_soft) overlays wbuf+invs
  const size_t wbytes = ((size_t)(NE+NN)*8*4 + 255) & ~(size_t)255;
  const size_t ibytes = (size_t)NN*8*4;
  const size_t xbytes = (size_t)NP*64*2;
  char* un = (char*)alloc(wbytes + ibytes > xbytes ? wbytes + ibytes : xbytes);
  u16*   Xp   = (u16*)un;
  float* wbuf = (float*)un;
  float* invs = (float*)(un + wbytes);
  float* asb = (float*)alloc((size_t)NN*8*4);
  float* adb = (float*)alloc((size_t)NN*8*4);
  int* counts= (int*)alloc((size_t)NN*4);
  int* cursor= (int*)alloc((size_t)NN*4);
  int* indptr= (int*)alloc((size_t)(NN+1)*4);
  int* srcs  = (int*)alloc((size_t)(NE+NN)*4);
  float* pooled = (float*)alloc((size_t)NG*768*4);
  float* gbuf   = (float*)alloc((size_t)NG*256*4);
  int* gcnt  = (int*)alloc((size_t)NG*4);
  u16* cvt   = (u16*)alloc((size_t)320*1024*2);
  int* flag  = (int*)alloc(256);

  // conversion jobs for all small params (everything except x, Win, W1, W2, W3)
  CvtJobs jobs; int ji = 0; int cvtoff = 0;
  auto addjob = [&](int idx, int n) -> u16* {
    jobs.src[ji] = d_in[idx]; jobs.n[ji] = n; jobs.dstoff[ji] = cvtoff; ji++;
    u16* r = cvt + cvtoff; cvtoff = (cvtoff + n + 15) & ~15; return r;
  };
  u16* cb_in= addjob(4, 256);
  u16* cas1 = addjob(6, 1024);  u16* cad1 = addjob(7, 1024);
  u16* cb1  = addjob(8, 1024);  u16* cg1  = addjob(9, 1024);  u16* cbe1 = addjob(10, 1024);
  u16* cas2 = addjob(12, 1024); u16* cad2 = addjob(13, 1024);
  u16* cb2  = addjob(14, 1024); u16* cg2  = addjob(15, 1024); u16* cbe2 = addjob(16, 1024);
  u16* cas3 = addjob(18, 1024); u16* cad3 = addjob(19, 1024);
  u16* cb3  = addjob(20, 256);  u16* cg3  = addjob(21, 256);  u16* cbe3 = addjob(22, 256);
  u16* cWp  = addjob(23, 196608); u16* cbp = addjob(24, 256);
  u16* cWv1 = addjob(25, 32768);  u16* cbv1= addjob(26, 128);
  u16* cWv2 = addjob(27, 8192);   u16* cbv2= addjob(28, 64);
  u16* cWv3 = addjob(29, 128);    u16* cbv3= addjob(30, 2);
  u16* cWt1 = addjob(31, 32768);  u16* cbt1= addjob(32, 128);
  u16* cWt2 = addjob(33, 8192);   u16* cbt2= addjob(34, 64);
  u16* cWt3 = addjob(35, 640);    u16* cbt3= addjob(36, 10);
  u16* cWc1 = addjob(37, 16384);  u16* cbc1= addjob(38, 64);
  u16* cWc2 = addjob(39, 64);     u16* cbc2= addjob(40, 1);

  // dtype detection + conversions
  k_detect<<<1, 64, 0, stream>>>((const uint32_t*)d_in[3], flag);
  k_cvt<<<ji, 256, 0, stream>>>(jobs, flag, cvt);
  k_pad_x<<<(NP*64+255)/256, 256, 0, stream>>>(d_in[0], Xp, flag);
  k_pad_winT<<<(256*64+255)/256, 256, 0, stream>>>(d_in[3], WinT, flag);
  k_transpose<<<(256*1024+255)/256, 256, 0, stream>>>(d_in[5], W1t, 256, 1024, flag);
  k_transpose<<<(1024*1024+255)/256, 256, 0, stream>>>(d_in[11], W2t, 1024, 1024, flag);
  k_transpose<<<(1024*1024+255)/256, 256, 0, stream>>>(d_in[17], W3t, 1024, 1024, flag);

  // CSR build
  k_init_counts<<<(NN+255)/256, 256, 0, stream>>>(counts);
  k_count<<<(NE+255)/256, 256, 0, stream>>>(eidx, counts);
  k_scan<<<1, 1024, 0, stream>>>(counts, indptr, cursor);
  k_fill<<<(NE+NN+255)/256, 256, 0, stream>>>(eidx, cursor, srcs);

  // input transform: relu(x @ Win + b_in) -> bufA [NP,256]
  k_gemm_bt<64,true,1><<<dim3((NP/128)*2), 256, 0, stream>>>(Xp, WinT, bufA, 256, cb_in);

  // layer 1 (H=8, C=128)
  k_gemm256<256,4><<<dim3((NP/256)*4), 512, 0, stream>>>(bufA, W1t, bufH, 1024);
  k_alpha<8><<<(NN+3)/4, 256, 0, stream>>>(bufH, cas1, cad1, asb, adb);
  k_soft<8><<<(NN*8+255)/256, 256, 0, stream>>>(asb, adb, indptr, srcs, wbuf, invs);
  k_agg2<8,128,false><<<NP, 256, 0, stream>>>(bufH, wbuf, invs, indptr, srcs, cb1, cg1, cbe1, bufA);

  // layer 2 (H=8, C=128)
  k_gemm256<1024,4><<<dim3((NP/256)*4), 512, 0, stream>>>(bufA, W2t, bufH, 1024);
  k_alpha<8><<<(NN+3)/4, 256, 0, stream>>>(bufH, cas2, cad2, asb, adb);
  k_soft<8><<<(NN*8+255)/256, 256, 0, stream>>>(asb, adb, indptr, srcs, wbuf, invs);
  k_agg2<8,128,false><<<NP, 256, 0, stream>>>(bufH, wbuf, invs, indptr, srcs, cb2, cg2, cbe2, bufA);

  // layer 3 (H=4, C=256, mean over heads)
  k_gemm256<1024,4><<<dim3((NP/256)*4), 512, 0, stream>>>(bufA, W3t, bufH, 1024);
  k_alpha<4><<<(NN+3)/4, 256, 0, stream>>>(bufH, cas3, cad3, asb, adb);
  k_soft<4><<<(NN*4+255)/256, 256, 0, stream>>>(asb, adb, indptr, srcs, wbuf, invs);
  k_agg2<4,256,true><<<NP, 256, 0, stream>>>(bufH, wbuf, invs, indptr, srcs, cb3, cg3, cbe3, bufA);

  // pooling + readout
  k_pool_init<<<(NG*768+255)/256, 256, 0, stream>>>(pooled, gcnt);
  k_pool1<<<(NN+63)/64, 256, 0, stream>>>(bufA, batch, pooled, gcnt);
  k_pool_fin<<<(NG*256+255)/256, 256, 0, stream>>>(pooled, gcnt);
  k_gvec<<<NG, 256, 0, stream>>>(pooled, cWp, cbp, gbuf);
  k_heads<<<NG, 128, 0, stream>>>(gbuf, cWv1,cbv1,cWv2,cbv2,cWv3,cbv3,
                                  cWt1,cbt1,cWt2,cbt2,cWt3,cbt3, cWc1,cbc1,cWc2,cbc2,
                                  d_out, flag);
}

// Round 7
// 1013.624 us; speedup vs baseline: 1.1374x; 1.1188x over previous
//
#include <hip/hip_runtime.h>
#include <stdint.h>

static constexpr int NN = 50000;   // real nodes
static constexpr int NP = 50176;   // padded rows = 196*256 (also /128 = 392)
static constexpr int NE = 200000;  // edges before self-loops
static constexpr int NG = 64;      // graphs
#define BN_S 0.99999500003749968f  // 1/sqrt(1+1e-5)

typedef __bf16 bf16x8 __attribute__((ext_vector_type(8)));
typedef float  f32x4  __attribute__((ext_vector_type(4)));
typedef __attribute__((address_space(1))) void* as1p;
typedef __attribute__((address_space(3))) void* as3p;
typedef unsigned short u16;

__device__ __forceinline__ float b2f(u16 u){ union{uint32_t i;float f;}x; x.i=((uint32_t)u)<<16; return x.f; }
__device__ __forceinline__ float lo_f(uint32_t u){ union{uint32_t i;float f;}x; x.i=u<<16; return x.f; }
__device__ __forceinline__ float hi_f(uint32_t u){ union{uint32_t i;float f;}x; x.i=u&0xffff0000u; return x.f; }
__device__ __forceinline__ u16 f2b(float f){
  union{float f;uint32_t i;}x; x.f=f;
  return (u16)((x.i + 0x7fffu + ((x.i>>16)&1u)) >> 16);
}
__device__ __forceinline__ void lds_cp16(const void* g, void* l){
  __builtin_amdgcn_global_load_lds((as1p)g, (as3p)l, 16, 0, 0);
}

// ---------------- dtype detection ----------------
__global__ void k_detect(const uint32_t* __restrict__ win, int* __restrict__ flag){
  const int lane = threadIdx.x;       // 64 threads
  const uint32_t w = win[lane];
  const int e = (w >> 7) & 0xFF;
  const bool band = (e >= 100 && e <= 140) || ((w & 0xFFFFu) == 0u);
  unsigned long long m = __ballot(band);
  if (lane == 0) *flag = (__popcll(m) < 32) ? 1 : 0;   // 1 => inputs are f32
}

// ---------------- small-param conversion to bf16 arena ----------------
struct CvtJobs {
  const void* src[34];
  int n[34];
  int dstoff[34];
};
__global__ __launch_bounds__(256) void k_cvt(CvtJobs jobs, const int* __restrict__ flag,
                                             u16* __restrict__ dst0){
  const int j = blockIdx.x;
  const int n = jobs.n[j];
  u16* dst = dst0 + jobs.dstoff[j];
  if (*flag){
    const float* s = (const float*)jobs.src[j];
    for (int i = threadIdx.x; i < n; i += 256) dst[i] = f2b(s[i]);
  } else {
    const u16* s = (const u16*)jobs.src[j];
    for (int i = threadIdx.x; i < n; i += 256) dst[i] = s[i];
  }
}

// ---------------- prep kernels (dual dtype) ----------------
__global__ void k_pad_x(const void* __restrict__ x, u16* __restrict__ xp, const int* __restrict__ flag){
  int i = blockIdx.x*256 + threadIdx.x;           // over NP*64
  if (i >= NP*64) return;
  int n = i >> 6, k = i & 63;
  u16 v = 0;
  if (n < NN && k < 62)
    v = (*flag) ? f2b(((const float*)x)[n*62 + k]) : ((const u16*)x)[n*62 + k];
  xp[i] = v;
}
__global__ void k_pad_winT(const void* __restrict__ w, u16* __restrict__ wt, const int* __restrict__ flag){
  int i = blockIdx.x*256 + threadIdx.x;           // over 256*64, i = o*64+k
  if (i >= 256*64) return;
  int o = i >> 6, k = i & 63;
  u16 v = 0;
  if (k < 62)
    v = (*flag) ? f2b(((const float*)w)[k*256 + o]) : ((const u16*)w)[k*256 + o];
  wt[i] = v;
}
__global__ void k_transpose(const void* __restrict__ w, u16* __restrict__ wt, int K, int NO,
                            const int* __restrict__ flag){
  int i = blockIdx.x*256 + threadIdx.x;           // i = k*NO + o
  if (i >= K*NO) return;
  int k = i / NO, o = i - k*NO;
  u16 v = (*flag) ? f2b(((const float*)w)[i]) : ((const u16*)w)[i];
  wt[(size_t)o*K + k] = v;
}

// ---------------- CSR build ----------------
__global__ void k_init_counts(int* counts){
  int i = blockIdx.x*256 + threadIdx.x;
  if (i < NN) counts[i] = 1;                       // self-loop
}
__global__ void k_count(const int* __restrict__ eidx, int* counts){
  int e = blockIdx.x*256 + threadIdx.x;
  if (e < NE) atomicAdd(&counts[eidx[NE + e]], 1);
}
__global__ __launch_bounds__(1024) void k_scan(const int* __restrict__ counts,
                                               int* __restrict__ indptr, int* __restrict__ cursor){
  __shared__ int sums[1024];
  const int t = threadIdx.x;
  const int strip = (NN + 1023)/1024;
  int lo = t*strip, hi = lo+strip < NN ? lo+strip : NN;
  int s = 0;
  for (int i=lo;i<hi;i++) s += counts[i];
  sums[t] = s; __syncthreads();
  for (int off=1; off<1024; off<<=1){
    int v = (t>=off) ? sums[t-off] : 0;
    __syncthreads();
    sums[t] += v;
    __syncthreads();
  }
  int base = t ? sums[t-1] : 0;
  for (int i=lo;i<hi;i++){ indptr[i]=base; cursor[i]=base; base += counts[i]; }
  if (t == 1023) indptr[NN] = sums[1023];
}
__global__ void k_fill(const int* __restrict__ eidx, int* cursor, int* __restrict__ srcs){
  int i = blockIdx.x*256 + threadIdx.x;
  if (i >= NE + NN) return;
  int s, d;
  if (i < NE){ s = eidx[i]; d = eidx[NE+i]; }
  else { s = d = i - NE; }
  int p = atomicAdd(&cursor[d], 1);
  srcs[p] = s;
}

// ---------------- 128-tile MFMA GEMM (kept for the K=64 input transform) ----------------
template<int K, bool EPI, int BNSH>
__global__ __launch_bounds__(256) void k_gemm_bt(const u16* __restrict__ A, const u16* __restrict__ B,
                                                 u16* __restrict__ C, int ldc, const u16* __restrict__ bias){
  __shared__ __align__(16) u16 As[128*64];
  __shared__ __align__(16) u16 Bs[128*64];
  const int tid = threadIdx.x;
  const int lane = tid & 63, wv = tid >> 6;
  const int bid = blockIdx.x;
  const size_t bm = bid >> BNSH, bn = bid & ((1<<BNSH)-1);
  const u16* Ab = A + bm*128*(size_t)K;
  const u16* Bb = B + bn*128*(size_t)K;
  f32x4 acc[4][4] = {};
  const int wm = (wv>>1)*64, wn = (wv&1)*64;
  const int r = lane & 15, kg = lane >> 4;
  const int srow = wv*32 + (lane>>3);
  const int scol = (lane&7)*8;
  for (int kt = 0; kt < K; kt += 64){
    #pragma unroll
    for (int i=0;i<4;i++){
      lds_cp16(Ab + (size_t)(srow + i*8)*K + kt + scol, (char*)As + (wv*4+i)*1024);
      lds_cp16(Bb + (size_t)(srow + i*8)*K + kt + scol, (char*)Bs + (wv*4+i)*1024);
    }
    __syncthreads();
    #pragma unroll
    for (int ks=0; ks<2; ks++){
      bf16x8 a[4], b[4];
      const int ko = ks*32 + kg*8;
      #pragma unroll
      for (int i=0;i<4;i++) a[i] = *(const bf16x8*)(As + (wm + i*16 + r)*64 + ko);
      #pragma unroll
      for (int j=0;j<4;j++) b[j] = *(const bf16x8*)(Bs + (wn + j*16 + r)*64 + ko);
      #pragma unroll
      for (int i=0;i<4;i++)
        #pragma unroll
        for (int j=0;j<4;j++)
          acc[i][j] = __builtin_amdgcn_mfma_f32_16x16x32_bf16(a[i], b[j], acc[i][j], 0, 0, 0);
    }
    __syncthreads();
  }
  const int rg = lane>>4, cl = lane&15;
  #pragma unroll
  for (int i=0;i<4;i++){
    #pragma unroll
    for (int j=0;j<4;j++){
      const int col = (int)bn*128 + wn + j*16 + cl;
      float bv = 0.f;
      if (EPI) bv = b2f(bias[col]);
      #pragma unroll
      for (int rr=0;rr<4;rr++){
        const int row = (int)bm*128 + wm + i*16 + rg*4 + rr;
        float v = acc[i][j][rr];
        if (EPI){ v += bv; v = v>0.f ? v : 0.f; }
        C[(size_t)row*ldc + col] = f2b(v);
      }
    }
  }
}

// ---------------- 256-tile 8-phase MFMA GEMM (T2 swizzle + T3 + T5) ----------------
// C[M,N] = A[M,K] @ B[N,K]^T.  512 threads = 8 waves (2 Mx4 N), per-wave 128x64 out.
// LDS: 2 x (A[256][64] | B[256][64]) = 128 KiB double buffer, compile-time offsets.
// T2 swizzle (rule #21): LDS dest stays linear for global_load_lds; the GLOBAL
// source 16B-slot is pre-swizzled slot^=(row&7), and reads XOR the same pattern.
template<int K, int BNT>
__global__ __launch_bounds__(512, 2) void k_gemm256(const u16* __restrict__ A, const u16* __restrict__ B,
                                                    u16* __restrict__ C, int ldc){
  __shared__ __align__(16) u16 lds[65536];        // 128 KiB
  const int tid = threadIdx.x;
  const int lane = tid & 63, wid = tid >> 6;
  const int wr = wid >> 2, wc = wid & 3;
  const int bm = blockIdx.x / BNT, bn = blockIdx.x % BNT;
  const u16* Ab = A + (size_t)bm*256*K;
  const u16* Bb = B + (size_t)bn*256*K;
  const int r = lane & 15, kg = lane >> 4;
  const int r7 = r & 7;
  f32x4 acc[8][4] = {};

  // stage half-tile `which` (0=Ah0,1=Ah1,2=Bh0,3=Bh1) of K-tile T into buffer at u16-offset wro.
  // Inverse-swizzled global source: thread's linear LDS slot (tid&7) receives
  // global slot (tid&7)^(row&7); row&7 == (tid>>3)&7 for both L iterations.
  auto stage = [&](int which, int T, int wro){
    const u16* src = (which < 2 ? Ab + (size_t)(which*128)*K
                                : Bb + (size_t)((which-2)*128)*K) + (size_t)T*64;
    u16* dst = lds + wro + (which >= 2 ? 16384 : 0) + (which & 1)*8192;
    const int gslot = (tid & 7) ^ ((tid >> 3) & 7);
    #pragma unroll
    for (int L = 0; L < 2; L++){
      const int off = L*4096 + tid*8;             // linear LDS dest (u16 units)
      lds_cp16(src + (size_t)(off >> 6)*K + gslot*8, dst + off);
    }
  };

  // one K-tile: 4 phases of {8x ds_read_b128(swizzled) ; prefetch ; barrier ; 16 MFMA ; barrier}
  // All 4 half-tile stages of T+1 issue in phases 0-1 (early) so the boundary
  // drain has ~2.5 phases of MFMA latency cover.
  auto do_tile = [&](int T, int rdo, int wro, bool prefetch){
    const u16* As_ = lds + rdo;
    const u16* Bs_ = lds + rdo + 16384;
    #pragma unroll
    for (int p = 0; p < 4; ++p){
      const int h = p >> 1, ks = p & 1;
      const int sl = ((ks*4 + kg) ^ r7) * 8;      // swizzled 16B slot (u16 units)
      bf16x8 a[4], b[4];
      const u16* ap = As_ + (wr*128 + h*64 + r)*64 + sl;
      const u16* bp = Bs_ + (wc*64  +        r)*64 + sl;
      #pragma unroll
      for (int m = 0; m < 4; m++) a[m] = *(const bf16x8*)(ap + m*1024);
      #pragma unroll
      for (int n = 0; n < 4; n++) b[n] = *(const bf16x8*)(bp + n*1024);
      if (prefetch){
        if (p == 0){ stage(0, T+1, wro); stage(1, T+1, wro); }
        else if (p == 1){ stage(2, T+1, wro); stage(3, T+1, wro); }
      }
      __builtin_amdgcn_s_barrier();
      __builtin_amdgcn_s_setprio(1);
      #pragma unroll
      for (int m = 0; m < 4; m++)
        #pragma unroll
        for (int n = 0; n < 4; n++)
          acc[h*4+m][n] = __builtin_amdgcn_mfma_f32_16x16x32_bf16(a[m], b[n], acc[h*4+m][n], 0, 0, 0);
      __builtin_amdgcn_s_setprio(0);
      if (p < 3) __builtin_amdgcn_s_barrier();
      else       __syncthreads();                 // tile boundary: drain vmcnt (next buffer ready)
    }
  };

  constexpr int NT = K/64;                        // even for all instantiations
  stage(0,0,0); stage(1,0,0); stage(2,0,0); stage(3,0,0);
  __syncthreads();
  for (int T = 0; T < NT; T += 2){
    do_tile(T,     0,     32768, true);           // stages T+1 into hi buffer
    do_tile(T+1, 32768,   0,     T+2 < NT);       // stages T+2 into lo buffer
  }

  const int cl = lane & 15, rg = lane >> 4;
  #pragma unroll
  for (int h = 0; h < 2; h++)
    #pragma unroll
    for (int m = 0; m < 4; m++)
      #pragma unroll
      for (int n = 0; n < 4; n++){
        const int col = bn*256 + wc*64 + n*16 + cl;
        #pragma unroll
        for (int rr = 0; rr < 4; rr++){
          const int row = bm*256 + wr*128 + h*64 + m*16 + rg*4 + rr;
          C[(size_t)row*ldc + col] = f2b(acc[h*4+m][n][rr]);
        }
      }
}

// ---------------- per-node attention dots ----------------
template<int H>
__global__ __launch_bounds__(256) void k_alpha(const u16* __restrict__ h,
                                               const u16* __restrict__ a_s, const u16* __restrict__ a_d,
                                               float* __restrict__ os, float* __restrict__ od){
  const int n = blockIdx.x*4 + (threadIdx.x>>6);
  if (n >= NN) return;
  const int lane = threadIdx.x & 63;
  const int c0 = lane*16;
  const uint4 hv0 = *(const uint4*)(h + (size_t)n*1024 + c0);
  const uint4 hv1 = *(const uint4*)(h + (size_t)n*1024 + c0 + 8);
  const uint4 sv0 = *(const uint4*)(a_s + c0);
  const uint4 sv1 = *(const uint4*)(a_s + c0 + 8);
  const uint4 dv0 = *(const uint4*)(a_d + c0);
  const uint4 dv1 = *(const uint4*)(a_d + c0 + 8);
  float ss = 0.f, sd = 0.f;
  uint32_t hu[8] = {hv0.x,hv0.y,hv0.z,hv0.w,hv1.x,hv1.y,hv1.z,hv1.w};
  uint32_t su[8] = {sv0.x,sv0.y,sv0.z,sv0.w,sv1.x,sv1.y,sv1.z,sv1.w};
  uint32_t du[8] = {dv0.x,dv0.y,dv0.z,dv0.w,dv1.x,dv1.y,dv1.z,dv1.w};
  #pragma unroll
  for (int q=0;q<8;q++){
    float h0 = lo_f(hu[q]), h1 = hi_f(hu[q]);
    ss += h0*lo_f(su[q]) + h1*hi_f(su[q]);
    sd += h0*lo_f(du[q]) + h1*hi_f(du[q]);
  }
  const int G = 64 / H;
  #pragma unroll
  for (int off=1; off<G; off<<=1){ ss += __shfl_xor(ss, off); sd += __shfl_xor(sd, off); }
  if ((lane & (G-1)) == 0){
    os[n*H + lane/G] = ss;
    od[n*H + lane/G] = sd;
  }
}

// ---------------- per-(node,head) segment softmax -> unnormalized weights ----------------
template<int H>
__global__ __launch_bounds__(256) void k_soft(const float* __restrict__ asb, const float* __restrict__ adb,
                                              const int* __restrict__ indptr, const int* __restrict__ srcs,
                                              float* __restrict__ wbuf, float* __restrict__ invs){
  const int idx = blockIdx.x*256 + threadIdx.x;
  if (idx >= NN*H) return;
  const int n = idx / H, hh = idx - n*H;
  const float adn = adb[idx];
  const int p0 = indptr[n], p1 = indptr[n+1];
  float m = -1e30f;
  for (int p = p0; p < p1; ++p){
    float t = asb[srcs[p]*H + hh] + adn;
    float v = t > 0.f ? t : 0.2f*t;
    m = fmaxf(m, v);
  }
  float s = 0.f;
  for (int p = p0; p < p1; ++p){
    float t = asb[srcs[p]*H + hh] + adn;
    float v = t > 0.f ? t : 0.2f*t;
    float e = __expf(v - m);
    wbuf[(size_t)p*H + hh] = e;
    s += e;
  }
  invs[idx] = 1.0f/(s + 1e-16f);
}

// ---------------- aggregation + bias + BN + relu (no LDS, no syncs) ----------------
template<int H, int C, bool FINAL>
__global__ __launch_bounds__(256) void k_agg2(const u16* __restrict__ h,
                                              const float* __restrict__ wbuf, const float* __restrict__ invs,
                                              const int* __restrict__ indptr, const int* __restrict__ srcs,
                                              const u16* __restrict__ bias, const u16* __restrict__ gamma,
                                              const u16* __restrict__ beta, u16* __restrict__ out){
  const int n = blockIdx.x;
  const int tid = threadIdx.x;
  constexpr int OUTW = FINAL ? C : H*C;
  if (n >= NN){
    for (int c = tid; c < OUTW; c += 256) out[(size_t)n*OUTW + c] = 0;
    return;
  }
  const int p0 = indptr[n], p1 = indptr[n+1];
  if (!FINAL){
    const int c0 = tid*4;
    const int hd = c0 >> 7;                        // C = 128
    float a0=0.f,a1=0.f,a2=0.f,a3=0.f;
    int p = p0;
    for (; p + 2 <= p1; p += 2){
      const int s0 = srcs[p], s1 = srcs[p+1];
      const float w0 = wbuf[(size_t)p*H + hd];
      const float w1 = wbuf[(size_t)(p+1)*H + hd];
      const ushort4 v0 = *(const ushort4*)(h + (size_t)s0*1024 + c0);
      const ushort4 v1 = *(const ushort4*)(h + (size_t)s1*1024 + c0);
      a0 += w0*b2f(v0.x) + w1*b2f(v1.x);
      a1 += w0*b2f(v0.y) + w1*b2f(v1.y);
      a2 += w0*b2f(v0.z) + w1*b2f(v1.z);
      a3 += w0*b2f(v0.w) + w1*b2f(v1.w);
    }
    if (p < p1){
      const int s0 = srcs[p];
      const float w0 = wbuf[(size_t)p*H + hd];
      const ushort4 v0 = *(const ushort4*)(h + (size_t)s0*1024 + c0);
      a0 += w0*b2f(v0.x); a1 += w0*b2f(v0.y); a2 += w0*b2f(v0.z); a3 += w0*b2f(v0.w);
    }
    const float is = invs[n*H + hd];
    float vv[4] = {a0,a1,a2,a3};
    u16 ov[4];
    #pragma unroll
    for (int i2=0;i2<4;i2++){
      const int c = c0 + i2;
      float v = (vv[i2]*is + b2f(bias[c])) * (b2f(gamma[c])*BN_S) + b2f(beta[c]);
      ov[i2] = f2b(v>0.f ? v : 0.f);
    }
    *(ushort4*)(out + (size_t)n*1024 + c0) = make_ushort4(ov[0],ov[1],ov[2],ov[3]);
  } else {
    const int c = tid;
    float a0=0.f,a1=0.f,a2=0.f,a3=0.f;
    for (int p = p0; p < p1; ++p){
      const int s = srcs[p];
      const float4 w4 = *(const float4*)(wbuf + (size_t)p*4);
      const u16* hr = h + (size_t)s*1024 + c;
      a0 += w4.x * b2f(hr[0]);
      a1 += w4.y * b2f(hr[256]);
      a2 += w4.z * b2f(hr[512]);
      a3 += w4.w * b2f(hr[768]);
    }
    const float4 is = *(const float4*)(invs + n*4);
    float meanv = 0.25f*(a0*is.x + a1*is.y + a2*is.z + a3*is.w);
    float v = (meanv + b2f(bias[c])) * (b2f(gamma[c])*BN_S) + b2f(beta[c]);
    out[(size_t)n*C + c] = f2b(v>0.f ? v : 0.f);
  }
}

// ---------------- pooling (parallel, atomic segmented) ----------------
__global__ __launch_bounds__(256) void k_pool_init(float* __restrict__ pooled, int* __restrict__ gcnt){
  int i = blockIdx.x*256 + threadIdx.x;
  if (i < NG*768) pooled[i] = 0.f;
  if (i < NG) gcnt[i] = 0;
}
__global__ __launch_bounds__(256) void k_pool1(const u16* __restrict__ x3, const int* __restrict__ batch,
                                               float* __restrict__ pooled, int* __restrict__ gcnt){
  const int n0 = blockIdx.x*64;
  const int n1 = (n0+64 < NN) ? n0+64 : NN;
  if (n0 >= NN) return;
  const int t = threadIdx.x;
  float sum=0.f, mx=0.f;
  int curg = batch[n0];
  int segstart = n0;
  for (int n=n0; n<n1; ++n){
    const int g = batch[n];
    if (g != curg){
      atomicAdd(&pooled[curg*768+512+t], sum);
      atomicMax((unsigned int*)&pooled[curg*768+256+t], __float_as_uint(mx));
      if (t==0) atomicAdd(&gcnt[curg], n-segstart);
      sum=0.f; mx=0.f; curg=g; segstart=n;
    }
    float v = b2f(x3[(size_t)n*256+t]);
    sum += v; mx = fmaxf(mx, v);
  }
  atomicAdd(&pooled[curg*768+512+t], sum);
  atomicMax((unsigned int*)&pooled[curg*768+256+t], __float_as_uint(mx));
  if (t==0) atomicAdd(&gcnt[curg], n1-segstart);
}
__global__ __launch_bounds__(256) void k_pool_fin(float* __restrict__ pooled, const int* __restrict__ gcnt){
  int i = blockIdx.x*256 + threadIdx.x;
  if (i >= NG*256) return;
  int g = i>>8, c = i&255;
  float s = pooled[g*768+512+c];
  int cnt = gcnt[g];
  pooled[g*768+c] = s / (float)(cnt>1?cnt:1);
}

// ---------------- readout MLPs ----------------
__global__ __launch_bounds__(256) void k_gvec(const float* __restrict__ pooled, const u16* __restrict__ Wp,
                                              const u16* __restrict__ bp, float* __restrict__ gbuf){
  const int g = blockIdx.x, t = threadIdx.x;
  __shared__ float ps[768];
  for (int i=t;i<768;i+=256) ps[i] = pooled[g*768+i];
  __syncthreads();
  float acc = b2f(bp[t]);
  for (int k=0;k<768;k++) acc += ps[k]*b2f(Wp[k*256+t]);
  gbuf[g*256+t] = acc>0.f ? acc : 0.f;
}
__global__ __launch_bounds__(128) void k_heads(const float* __restrict__ gbuf,
    const u16* Wv1,const u16* bv1,const u16* Wv2,const u16* bv2,const u16* Wv3,const u16* bv3,
    const u16* Wt1,const u16* bt1,const u16* Wt2,const u16* bt2,const u16* Wt3,const u16* bt3,
    const u16* Wc1,const u16* bc1,const u16* Wc2,const u16* bc2,
    void* __restrict__ outp, const int* __restrict__ flag){
  const int g = blockIdx.x, t = threadIdx.x;
  const int f32o = *flag;
  u16* o16 = (u16*)outp;
  float* o32 = (float*)outp;
  __shared__ float gs[256], h1[128], h2[64];
  gs[t] = gbuf[g*256+t]; gs[t+128] = gbuf[g*256+t+128];
  __syncthreads();
  { float a = b2f(bv1[t]); for (int k=0;k<256;k++) a += gs[k]*b2f(Wv1[k*128+t]); h1[t] = a>0.f?a:0.f; }
  __syncthreads();
  if (t<64){ float a=b2f(bv2[t]); for(int k=0;k<128;k++) a += h1[k]*b2f(Wv2[k*64+t]); h2[t]=a>0.f?a:0.f; }
  __syncthreads();
  if (t<2){ float a=b2f(bv3[t]); for(int k=0;k<64;k++) a += h2[k]*b2f(Wv3[k*2+t]);
            if (f32o) o32[g*2+t]=a; else o16[g*2+t]=f2b(a); }
  __syncthreads();
  { float a = b2f(bt1[t]); for (int k=0;k<256;k++) a += gs[k]*b2f(Wt1[k*128+t]); h1[t] = a>0.f?a:0.f; }
  __syncthreads();
  if (t<64){ float a=b2f(bt2[t]); for(int k=0;k<128;k++) a += h1[k]*b2f(Wt2[k*64+t]); h2[t]=a>0.f?a:0.f; }
  __syncthreads();
  if (t<10){ float a=b2f(bt3[t]); for(int k=0;k<64;k++) a += h2[k]*b2f(Wt3[k*10+t]);
             if (f32o) o32[128 + g*10+t]=a; else o16[128 + g*10+t]=f2b(a); }
  __syncthreads();
  if (t<64){ float a=b2f(bc1[t]); for(int k=0;k<256;k++) a += gs[k]*b2f(Wc1[k*64+t]); h2[t]=a>0.f?a:0.f; }
  __syncthreads();
  if (t==0){
    float a=b2f(bc2[0]);
    for(int k=0;k<64;k++) a += h2[k]*b2f(Wc2[k]);
    float r = 1.f/(1.f+__expf(-a));
    if (f32o) o32[768+g]=r; else o16[768+g]=f2b(r);
  }
}

extern "C" void kernel_launch(void* const* d_in, const int* in_sizes, int n_in,
                              void* d_out, int out_size, void* d_ws, size_t ws_size,
                              hipStream_t stream){
  (void)in_sizes; (void)n_in; (void)out_size; (void)ws_size;
  const int* eidx = (const int*)d_in[1];
  const int* batch= (const int*)d_in[2];

  char* ws = (char*)d_ws;
  size_t off = 0;
  auto alloc = [&](size_t bytes) -> void* {
    void* p = ws + off;
    off += (bytes + 255) & ~(size_t)255;
    return p;
  };
  u16* bufA  = (u16*)alloc((size_t)NP*1024*2);
  u16* bufH  = (u16*)alloc((size_t)NP*1024*2);
  u16* W1t   = (u16*)alloc((size_t)1024*256*2);
  u16* W2t   = (u16*)alloc((size_t)1024*1024*2);
  u16* W3t   = (u16*)alloc((size_t)1024*1024*2);
  u16* WinT  = (u16*)alloc((size_t)256*64*2);
  // union region: Xp (used only before first k_soft) overlays wbuf+invs
  const size_t wbytes = ((size_t)(NE+NN)*8*4 + 255) & ~(size_t)255;
  const size_t ibytes = (size_t)NN*8*4;
  const size_t xbytes = (size_t)NP*64*2;
  char* un = (char*)alloc(wbytes + ibytes > xbytes ? wbytes + ibytes : xbytes);
  u16*   Xp   = (u16*)un;
  float* wbuf = (float*)un;
  float* invs = (float*)(un + wbytes);
  float* asb = (float*)alloc((size_t)NN*8*4);
  float* adb = (float*)alloc((size_t)NN*8*4);
  int* counts= (int*)alloc((size_t)NN*4);
  int* cursor= (int*)alloc((size_t)NN*4);
  int* indptr= (int*)alloc((size_t)(NN+1)*4);
  int* srcs  = (int*)alloc((size_t)(NE+NN)*4);
  float* pooled = (float*)alloc((size_t)NG*768*4);
  float* gbuf   = (float*)alloc((size_t)NG*256*4);
  int* gcnt  = (int*)alloc((size_t)NG*4);
  u16* cvt   = (u16*)alloc((size_t)320*1024*2);
  int* flag  = (int*)alloc(256);

  // conversion jobs for all small params (everything except x, Win, W1, W2, W3)
  CvtJobs jobs; int ji = 0; int cvtoff = 0;
  auto addjob = [&](int idx, int n) -> u16* {
    jobs.src[ji] = d_in[idx]; jobs.n[ji] = n; jobs.dstoff[ji] = cvtoff; ji++;
    u16* r = cvt + cvtoff; cvtoff = (cvtoff + n + 15) & ~15; return r;
  };
  u16* cb_in= addjob(4, 256);
  u16* cas1 = addjob(6, 1024);  u16* cad1 = addjob(7, 1024);
  u16* cb1  = addjob(8, 1024);  u16* cg1  = addjob(9, 1024);  u16* cbe1 = addjob(10, 1024);
  u16* cas2 = addjob(12, 1024); u16* cad2 = addjob(13, 1024);
  u16* cb2  = addjob(14, 1024); u16* cg2  = addjob(15, 1024); u16* cbe2 = addjob(16, 1024);
  u16* cas3 = addjob(18, 1024); u16* cad3 = addjob(19, 1024);
  u16* cb3  = addjob(20, 256);  u16* cg3  = addjob(21, 256);  u16* cbe3 = addjob(22, 256);
  u16* cWp  = addjob(23, 196608); u16* cbp = addjob(24, 256);
  u16* cWv1 = addjob(25, 32768);  u16* cbv1= addjob(26, 128);
  u16* cWv2 = addjob(27, 8192);   u16* cbv2= addjob(28, 64);
  u16* cWv3 = addjob(29, 128);    u16* cbv3= addjob(30, 2);
  u16* cWt1 = addjob(31, 32768);  u16* cbt1= addjob(32, 128);
  u16* cWt2 = addjob(33, 8192);   u16* cbt2= addjob(34, 64);
  u16* cWt3 = addjob(35, 640);    u16* cbt3= addjob(36, 10);
  u16* cWc1 = addjob(37, 16384);  u16* cbc1= addjob(38, 64);
  u16* cWc2 = addjob(39, 64);     u16* cbc2= addjob(40, 1);

  // dtype detection + conversions
  k_detect<<<1, 64, 0, stream>>>((const uint32_t*)d_in[3], flag);
  k_cvt<<<ji, 256, 0, stream>>>(jobs, flag, cvt);
  k_pad_x<<<(NP*64+255)/256, 256, 0, stream>>>(d_in[0], Xp, flag);
  k_pad_winT<<<(256*64+255)/256, 256, 0, stream>>>(d_in[3], WinT, flag);
  k_transpose<<<(256*1024+255)/256, 256, 0, stream>>>(d_in[5], W1t, 256, 1024, flag);
  k_transpose<<<(1024*1024+255)/256, 256, 0, stream>>>(d_in[11], W2t, 1024, 1024, flag);
  k_transpose<<<(1024*1024+255)/256, 256, 0, stream>>>(d_in[17], W3t, 1024, 1024, flag);

  // CSR build
  k_init_counts<<<(NN+255)/256, 256, 0, stream>>>(counts);
  k_count<<<(NE+255)/256, 256, 0, stream>>>(eidx, counts);
  k_scan<<<1, 1024, 0, stream>>>(counts, indptr, cursor);
  k_fill<<<(NE+NN+255)/256, 256, 0, stream>>>(eidx, cursor, srcs);

  // input transform: relu(x @ Win + b_in) -> bufA [NP,256]
  k_gemm_bt<64,true,1><<<dim3((NP/128)*2), 256, 0, stream>>>(Xp, WinT, bufA, 256, cb_in);

  // layer 1 (H=8, C=128)
  k_gemm256<256,4><<<dim3((NP/256)*4), 512, 0, stream>>>(bufA, W1t, bufH, 1024);
  k_alpha<8><<<(NN+3)/4, 256, 0, stream>>>(bufH, cas1, cad1, asb, adb);
  k_soft<8><<<(NN*8+255)/256, 256, 0, stream>>>(asb, adb, indptr, srcs, wbuf, invs);
  k_agg2<8,128,false><<<NP, 256, 0, stream>>>(bufH, wbuf, invs, indptr, srcs, cb1, cg1, cbe1, bufA);

  // layer 2 (H=8, C=128)
  k_gemm256<1024,4><<<dim3((NP/256)*4), 512, 0, stream>>>(bufA, W2t, bufH, 1024);
  k_alpha<8><<<(NN+3)/4, 256, 0, stream>>>(bufH, cas2, cad2, asb, adb);
  k_soft<8><<<(NN*8+255)/256, 256, 0, stream>>>(asb, adb, indptr, srcs, wbuf, invs);
  k_agg2<8,128,false><<<NP, 256, 0, stream>>>(bufH, wbuf, invs, indptr, srcs, cb2, cg2, cbe2, bufA);

  // layer 3 (H=4, C=256, mean over heads)
  k_gemm256<1024,4><<<dim3((NP/256)*4), 512, 0, stream>>>(bufA, W3t, bufH, 1024);
  k_alpha<4><<<(NN+3)/4, 256, 0, stream>>>(bufH, cas3, cad3, asb, adb);
  k_soft<4><<<(NN*4+255)/256, 256, 0, stream>>>(asb, adb, indptr, srcs, wbuf, invs);
  k_agg2<4,256,true><<<NP, 256, 0, stream>>>(bufH, wbuf, invs, indptr, srcs, cb3, cg3, cbe3, bufA);

  // pooling + readout
  k_pool_init<<<(NG*768+255)/256, 256, 0, stream>>>(pooled, gcnt);
  k_pool1<<<(NN+63)/64, 256, 0, stream>>>(bufA, batch, pooled, gcnt);
  k_pool_fin<<<(NG*256+255)/256, 256, 0, stream>>>(pooled, gcnt);
  k_gvec<<<NG, 256, 0, stream>>>(pooled, cWp, cbp, gbuf);
  k_heads<<<NG, 128, 0, stream>>>(gbuf, cWv1,cbv1,cWv2,cbv2,cWv3,cbv3,
                                  cWt1,cbt1,cWt2,cbt2,cWt3,cbt3, cWc1,cbc1,cWc2,cbc2,
                                  d_out, flag);
}

// Round 8
// 908.969 us; speedup vs baseline: 1.2684x; 1.1151x over previous
//
#include <hip/hip_runtime.h>
#include <stdint.h>

static constexpr int NN = 50000;   // real nodes
static constexpr int NP = 50176;   // padded rows = 196*256 (also /128 = 392)
static constexpr int NE = 200000;  // edges before self-loops
static constexpr int NG = 64;      // graphs
#define BN_S 0.99999500003749968f  // 1/sqrt(1+1e-5)

typedef __bf16 bf16x8 __attribute__((ext_vector_type(8)));
typedef float  f32x4  __attribute__((ext_vector_type(4)));
typedef __attribute__((address_space(1))) void* as1p;
typedef __attribute__((address_space(3))) void* as3p;
typedef unsigned short u16;

__device__ __forceinline__ float b2f(u16 u){ union{uint32_t i;float f;}x; x.i=((uint32_t)u)<<16; return x.f; }
__device__ __forceinline__ float lo_f(uint32_t u){ union{uint32_t i;float f;}x; x.i=u<<16; return x.f; }
__device__ __forceinline__ float hi_f(uint32_t u){ union{uint32_t i;float f;}x; x.i=u&0xffff0000u; return x.f; }
__device__ __forceinline__ u16 f2b(float f){
  union{float f;uint32_t i;}x; x.f=f;
  return (u16)((x.i + 0x7fffu + ((x.i>>16)&1u)) >> 16);
}
__device__ __forceinline__ void lds_cp16(const void* g, void* l){
  __builtin_amdgcn_global_load_lds((as1p)g, (as3p)l, 16, 0, 0);
}

// ---------------- dtype detection ----------------
__global__ void k_detect(const uint32_t* __restrict__ win, int* __restrict__ flag){
  const int lane = threadIdx.x;       // 64 threads
  const uint32_t w = win[lane];
  const int e = (w >> 7) & 0xFF;
  const bool band = (e >= 100 && e <= 140) || ((w & 0xFFFFu) == 0u);
  unsigned long long m = __ballot(band);
  if (lane == 0) *flag = (__popcll(m) < 32) ? 1 : 0;   // 1 => inputs are f32
}

// ---------------- small-param conversion to bf16 arena (element-parallel) ----------------
struct CvtJobs {
  const void* src[34];
  int n[34];
  int dstoff[34];
  int cum[35];       // cumulative element starts (unpadded)
  int njobs;
  int total;
};
__global__ __launch_bounds__(256) void k_cvt(CvtJobs jobs, const int* __restrict__ flag,
                                             u16* __restrict__ dst0){
  const int i = blockIdx.x*256 + threadIdx.x;
  if (i >= jobs.total) return;
  int lo = 0, hi = jobs.njobs - 1;
  while (lo < hi){ int mid = (lo+hi+1)>>1; if (jobs.cum[mid] <= i) lo = mid; else hi = mid-1; }
  const int j = lo;
  const int e = i - jobs.cum[j];
  u16 v = (*flag) ? f2b(((const float*)jobs.src[j])[e]) : ((const u16*)jobs.src[j])[e];
  dst0[jobs.dstoff[j] + e] = v;
}

// ---------------- prep kernels (dual dtype) ----------------
__global__ void k_pad_x(const void* __restrict__ x, u16* __restrict__ xp, const int* __restrict__ flag){
  int i = blockIdx.x*256 + threadIdx.x;           // over NP*64
  if (i >= NP*64) return;
  int n = i >> 6, k = i & 63;
  u16 v = 0;
  if (n < NN && k < 62)
    v = (*flag) ? f2b(((const float*)x)[n*62 + k]) : ((const u16*)x)[n*62 + k];
  xp[i] = v;
}
__global__ void k_pad_winT(const void* __restrict__ w, u16* __restrict__ wt, const int* __restrict__ flag){
  int i = blockIdx.x*256 + threadIdx.x;           // over 256*64, i = o*64+k
  if (i >= 256*64) return;
  int o = i >> 6, k = i & 63;
  u16 v = 0;
  if (k < 62)
    v = (*flag) ? f2b(((const float*)w)[k*256 + o]) : ((const u16*)w)[k*256 + o];
  wt[i] = v;
}
__global__ void k_transpose(const void* __restrict__ w, u16* __restrict__ wt, int K, int NO,
                            const int* __restrict__ flag){
  int i = blockIdx.x*256 + threadIdx.x;           // i = k*NO + o
  if (i >= K*NO) return;
  int k = i / NO, o = i - k*NO;
  u16 v = (*flag) ? f2b(((const float*)w)[i]) : ((const u16*)w)[i];
  wt[(size_t)o*K + k] = v;
}

// ---------------- CSR build ----------------
__global__ void k_init_counts(int* counts){
  int i = blockIdx.x*256 + threadIdx.x;
  if (i < NN) counts[i] = 1;                       // self-loop
}
__global__ void k_count(const int* __restrict__ eidx, int* counts){
  int e = blockIdx.x*256 + threadIdx.x;
  if (e < NE) atomicAdd(&counts[eidx[NE + e]], 1);
}
__global__ __launch_bounds__(1024) void k_scan(const int* __restrict__ counts,
                                               int* __restrict__ indptr, int* __restrict__ cursor){
  __shared__ int sums[1024];
  const int t = threadIdx.x;
  const int strip = (NN + 1023)/1024;
  int lo = t*strip, hi = lo+strip < NN ? lo+strip : NN;
  int s = 0;
  for (int i=lo;i<hi;i++) s += counts[i];
  sums[t] = s; __syncthreads();
  for (int off=1; off<1024; off<<=1){
    int v = (t>=off) ? sums[t-off] : 0;
    __syncthreads();
    sums[t] += v;
    __syncthreads();
  }
  int base = t ? sums[t-1] : 0;
  for (int i=lo;i<hi;i++){ indptr[i]=base; cursor[i]=base; base += counts[i]; }
  if (t == 1023) indptr[NN] = sums[1023];
}
__global__ void k_fill(const int* __restrict__ eidx, int* cursor, int* __restrict__ srcs){
  int i = blockIdx.x*256 + threadIdx.x;
  if (i >= NE + NN) return;
  int s, d;
  if (i < NE){ s = eidx[i]; d = eidx[NE+i]; }
  else { s = d = i - NE; }
  int p = atomicAdd(&cursor[d], 1);
  srcs[p] = s;
}

// ---------------- 128-tile MFMA GEMM (kept for the K=64 input transform) ----------------
template<int K, bool EPI, int BNSH>
__global__ __launch_bounds__(256) void k_gemm_bt(const u16* __restrict__ A, const u16* __restrict__ B,
                                                 u16* __restrict__ C, int ldc, const u16* __restrict__ bias){
  __shared__ __align__(16) u16 As[128*64];
  __shared__ __align__(16) u16 Bs[128*64];
  const int tid = threadIdx.x;
  const int lane = tid & 63, wv = tid >> 6;
  const int bid = blockIdx.x;
  const size_t bm = bid >> BNSH, bn = bid & ((1<<BNSH)-1);
  const u16* Ab = A + bm*128*(size_t)K;
  const u16* Bb = B + bn*128*(size_t)K;
  f32x4 acc[4][4] = {};
  const int wm = (wv>>1)*64, wn = (wv&1)*64;
  const int r = lane & 15, kg = lane >> 4;
  const int srow = wv*32 + (lane>>3);
  const int scol = (lane&7)*8;
  for (int kt = 0; kt < K; kt += 64){
    #pragma unroll
    for (int i=0;i<4;i++){
      lds_cp16(Ab + (size_t)(srow + i*8)*K + kt + scol, (char*)As + (wv*4+i)*1024);
      lds_cp16(Bb + (size_t)(srow + i*8)*K + kt + scol, (char*)Bs + (wv*4+i)*1024);
    }
    __syncthreads();
    #pragma unroll
    for (int ks=0; ks<2; ks++){
      bf16x8 a[4], b[4];
      const int ko = ks*32 + kg*8;
      #pragma unroll
      for (int i=0;i<4;i++) a[i] = *(const bf16x8*)(As + (wm + i*16 + r)*64 + ko);
      #pragma unroll
      for (int j=0;j<4;j++) b[j] = *(const bf16x8*)(Bs + (wn + j*16 + r)*64 + ko);
      #pragma unroll
      for (int i=0;i<4;i++)
        #pragma unroll
        for (int j=0;j<4;j++)
          acc[i][j] = __builtin_amdgcn_mfma_f32_16x16x32_bf16(a[i], b[j], acc[i][j], 0, 0, 0);
    }
    __syncthreads();
  }
  const int rg = lane>>4, cl = lane&15;
  #pragma unroll
  for (int i=0;i<4;i++){
    #pragma unroll
    for (int j=0;j<4;j++){
      const int col = (int)bn*128 + wn + j*16 + cl;
      float bv = 0.f;
      if (EPI) bv = b2f(bias[col]);
      #pragma unroll
      for (int rr=0;rr<4;rr++){
        const int row = (int)bm*128 + wm + i*16 + rg*4 + rr;
        float v = acc[i][j][rr];
        if (EPI){ v += bv; v = v>0.f ? v : 0.f; }
        C[(size_t)row*ldc + col] = f2b(v);
      }
    }
  }
}

// ---------------- 256-tile 8-phase MFMA GEMM (T2 swizzle + T3 + T5) ----------------
// C[M,N] = A[M,K] @ B[N,K]^T.  512 threads = 8 waves (2 Mx4 N), per-wave 128x64 out.
// LDS: 2 x (A[256][64] | B[256][64]) = 128 KiB double buffer, compile-time offsets.
// T2 swizzle (rule #21): LDS dest stays linear for global_load_lds; the GLOBAL
// source 16B-slot is pre-swizzled slot^=(row&7), and reads XOR the same pattern.
template<int K, int BNT>
__global__ __launch_bounds__(512, 2) void k_gemm256(const u16* __restrict__ A, const u16* __restrict__ B,
                                                    u16* __restrict__ C, int ldc){
  __shared__ __align__(16) u16 lds[65536];        // 128 KiB
  const int tid = threadIdx.x;
  const int lane = tid & 63, wid = tid >> 6;
  const int wr = wid >> 2, wc = wid & 3;
  const int bm = blockIdx.x / BNT, bn = blockIdx.x % BNT;
  const u16* Ab = A + (size_t)bm*256*K;
  const u16* Bb = B + (size_t)bn*256*K;
  const int r = lane & 15, kg = lane >> 4;
  const int r7 = r & 7;
  f32x4 acc[8][4] = {};

  auto stage = [&](int which, int T, int wro){
    const u16* src = (which < 2 ? Ab + (size_t)(which*128)*K
                                : Bb + (size_t)((which-2)*128)*K) + (size_t)T*64;
    u16* dst = lds + wro + (which >= 2 ? 16384 : 0) + (which & 1)*8192;
    const int gslot = (tid & 7) ^ ((tid >> 3) & 7);
    #pragma unroll
    for (int L = 0; L < 2; L++){
      const int off = L*4096 + tid*8;             // linear LDS dest (u16 units)
      lds_cp16(src + (size_t)(off >> 6)*K + gslot*8, dst + off);
    }
  };

  auto do_tile = [&](int T, int rdo, int wro, bool prefetch){
    const u16* As_ = lds + rdo;
    const u16* Bs_ = lds + rdo + 16384;
    #pragma unroll
    for (int p = 0; p < 4; ++p){
      const int h = p >> 1, ks = p & 1;
      const int sl = ((ks*4 + kg) ^ r7) * 8;      // swizzled 16B slot (u16 units)
      bf16x8 a[4], b[4];
      const u16* ap = As_ + (wr*128 + h*64 + r)*64 + sl;
      const u16* bp = Bs_ + (wc*64  +        r)*64 + sl;
      #pragma unroll
      for (int m = 0; m < 4; m++) a[m] = *(const bf16x8*)(ap + m*1024);
      #pragma unroll
      for (int n = 0; n < 4; n++) b[n] = *(const bf16x8*)(bp + n*1024);
      if (prefetch){
        if (p == 0){ stage(0, T+1, wro); stage(1, T+1, wro); }
        else if (p == 1){ stage(2, T+1, wro); stage(3, T+1, wro); }
      }
      __builtin_amdgcn_s_barrier();
      __builtin_amdgcn_s_setprio(1);
      #pragma unroll
      for (int m = 0; m < 4; m++)
        #pragma unroll
        for (int n = 0; n < 4; n++)
          acc[h*4+m][n] = __builtin_amdgcn_mfma_f32_16x16x32_bf16(a[m], b[n], acc[h*4+m][n], 0, 0, 0);
      __builtin_amdgcn_s_setprio(0);
      if (p < 3) __builtin_amdgcn_s_barrier();
      else       __syncthreads();                 // tile boundary: drain vmcnt (next buffer ready)
    }
  };

  constexpr int NT = K/64;                        // even for all instantiations
  stage(0,0,0); stage(1,0,0); stage(2,0,0); stage(3,0,0);
  __syncthreads();
  for (int T = 0; T < NT; T += 2){
    do_tile(T,     0,     32768, true);           // stages T+1 into hi buffer
    do_tile(T+1, 32768,   0,     T+2 < NT);       // stages T+2 into lo buffer
  }

  const int cl = lane & 15, rg = lane >> 4;
  #pragma unroll
  for (int h = 0; h < 2; h++)
    #pragma unroll
    for (int m = 0; m < 4; m++)
      #pragma unroll
      for (int n = 0; n < 4; n++){
        const int col = bn*256 + wc*64 + n*16 + cl;
        #pragma unroll
        for (int rr = 0; rr < 4; rr++){
          const int row = bm*256 + wr*128 + h*64 + m*16 + rg*4 + rr;
          C[(size_t)row*ldc + col] = f2b(acc[h*4+m][n][rr]);
        }
      }
}

// ---------------- per-node attention dots ----------------
template<int H>
__global__ __launch_bounds__(256) void k_alpha(const u16* __restrict__ h,
                                               const u16* __restrict__ a_s, const u16* __restrict__ a_d,
                                               float* __restrict__ os, float* __restrict__ od){
  const int n = blockIdx.x*4 + (threadIdx.x>>6);
  if (n >= NN) return;
  const int lane = threadIdx.x & 63;
  const int c0 = lane*16;
  const uint4 hv0 = *(const uint4*)(h + (size_t)n*1024 + c0);
  const uint4 hv1 = *(const uint4*)(h + (size_t)n*1024 + c0 + 8);
  const uint4 sv0 = *(const uint4*)(a_s + c0);
  const uint4 sv1 = *(const uint4*)(a_s + c0 + 8);
  const uint4 dv0 = *(const uint4*)(a_d + c0);
  const uint4 dv1 = *(const uint4*)(a_d + c0 + 8);
  float ss = 0.f, sd = 0.f;
  uint32_t hu[8] = {hv0.x,hv0.y,hv0.z,hv0.w,hv1.x,hv1.y,hv1.z,hv1.w};
  uint32_t su[8] = {sv0.x,sv0.y,sv0.z,sv0.w,sv1.x,sv1.y,sv1.z,sv1.w};
  uint32_t du[8] = {dv0.x,dv0.y,dv0.z,dv0.w,dv1.x,dv1.y,dv1.z,dv1.w};
  #pragma unroll
  for (int q=0;q<8;q++){
    float h0 = lo_f(hu[q]), h1 = hi_f(hu[q]);
    ss += h0*lo_f(su[q]) + h1*hi_f(su[q]);
    sd += h0*lo_f(du[q]) + h1*hi_f(du[q]);
  }
  const int G = 64 / H;
  #pragma unroll
  for (int off=1; off<G; off<<=1){ ss += __shfl_xor(ss, off); sd += __shfl_xor(sd, off); }
  if ((lane & (G-1)) == 0){
    os[n*H + lane/G] = ss;
    od[n*H + lane/G] = sd;
  }
}

// ---------------- per-(node,head) segment softmax -> unnormalized weights ----------------
template<int H>
__global__ __launch_bounds__(256) void k_soft(const float* __restrict__ asb, const float* __restrict__ adb,
                                              const int* __restrict__ indptr, const int* __restrict__ srcs,
                                              float* __restrict__ wbuf, float* __restrict__ invs){
  const int idx = blockIdx.x*256 + threadIdx.x;
  if (idx >= NN*H) return;
  const int n = idx / H, hh = idx - n*H;
  const float adn = adb[idx];
  const int p0 = indptr[n], p1 = indptr[n+1];
  float m = -1e30f;
  for (int p = p0; p < p1; ++p){
    float t = asb[srcs[p]*H + hh] + adn;
    float v = t > 0.f ? t : 0.2f*t;
    m = fmaxf(m, v);
  }
  float s = 0.f;
  for (int p = p0; p < p1; ++p){
    float t = asb[srcs[p]*H + hh] + adn;
    float v = t > 0.f ? t : 0.2f*t;
    float e = __expf(v - m);
    wbuf[(size_t)p*H + hh] = e;
    s += e;
  }
  invs[idx] = 1.0f/(s + 1e-16f);
}

// ---------------- aggregation + bias + BN + relu (no LDS, no syncs) ----------------
template<int H, int C, bool FINAL>
__global__ __launch_bounds__(256) void k_agg2(const u16* __restrict__ h,
                                              const float* __restrict__ wbuf, const float* __restrict__ invs,
                                              const int* __restrict__ indptr, const int* __restrict__ srcs,
                                              const u16* __restrict__ bias, const u16* __restrict__ gamma,
                                              const u16* __restrict__ beta, u16* __restrict__ out){
  const int n = blockIdx.x;
  const int tid = threadIdx.x;
  constexpr int OUTW = FINAL ? C : H*C;
  if (n >= NN){
    for (int c = tid; c < OUTW; c += 256) out[(size_t)n*OUTW + c] = 0;
    return;
  }
  const int p0 = indptr[n], p1 = indptr[n+1];
  if (!FINAL){
    const int c0 = tid*4;
    const int hd = c0 >> 7;                        // C = 128
    float a0=0.f,a1=0.f,a2=0.f,a3=0.f;
    int p = p0;
    for (; p + 2 <= p1; p += 2){
      const int s0 = srcs[p], s1 = srcs[p+1];
      const float w0 = wbuf[(size_t)p*H + hd];
      const float w1 = wbuf[(size_t)(p+1)*H + hd];
      const ushort4 v0 = *(const ushort4*)(h + (size_t)s0*1024 + c0);
      const ushort4 v1 = *(const ushort4*)(h + (size_t)s1*1024 + c0);
      a0 += w0*b2f(v0.x) + w1*b2f(v1.x);
      a1 += w0*b2f(v0.y) + w1*b2f(v1.y);
      a2 += w0*b2f(v0.z) + w1*b2f(v1.z);
      a3 += w0*b2f(v0.w) + w1*b2f(v1.w);
    }
    if (p < p1){
      const int s0 = srcs[p];
      const float w0 = wbuf[(size_t)p*H + hd];
      const ushort4 v0 = *(const ushort4*)(h + (size_t)s0*1024 + c0);
      a0 += w0*b2f(v0.x); a1 += w0*b2f(v0.y); a2 += w0*b2f(v0.z); a3 += w0*b2f(v0.w);
    }
    const float is = invs[n*H + hd];
    float vv[4] = {a0,a1,a2,a3};
    u16 ov[4];
    #pragma unroll
    for (int i2=0;i2<4;i2++){
      const int c = c0 + i2;
      float v = (vv[i2]*is + b2f(bias[c])) * (b2f(gamma[c])*BN_S) + b2f(beta[c]);
      ov[i2] = f2b(v>0.f ? v : 0.f);
    }
    *(ushort4*)(out + (size_t)n*1024 + c0) = make_ushort4(ov[0],ov[1],ov[2],ov[3]);
  } else {
    const int c = tid;
    float a0=0.f,a1=0.f,a2=0.f,a3=0.f;
    for (int p = p0; p < p1; ++p){
      const int s = srcs[p];
      const float4 w4 = *(const float4*)(wbuf + (size_t)p*4);
      const u16* hr = h + (size_t)s*1024 + c;
      a0 += w4.x * b2f(hr[0]);
      a1 += w4.y * b2f(hr[256]);
      a2 += w4.z * b2f(hr[512]);
      a3 += w4.w * b2f(hr[768]);
    }
    const float4 is = *(const float4*)(invs + n*4);
    float meanv = 0.25f*(a0*is.x + a1*is.y + a2*is.z + a3*is.w);
    float v = (meanv + b2f(bias[c])) * (b2f(gamma[c])*BN_S) + b2f(beta[c]);
    out[(size_t)n*C + c] = f2b(v>0.f ? v : 0.f);
  }
}

// ---------------- pooling (parallel, atomic segmented) ----------------
__global__ __launch_bounds__(256) void k_pool_init(float* __restrict__ pooled, int* __restrict__ gcnt){
  int i = blockIdx.x*256 + threadIdx.x;
  if (i < NG*768) pooled[i] = 0.f;
  if (i < NG) gcnt[i] = 0;
}
__global__ __launch_bounds__(256) void k_pool1(const u16* __restrict__ x3, const int* __restrict__ batch,
                                               float* __restrict__ pooled, int* __restrict__ gcnt){
  const int n0 = blockIdx.x*64;
  const int n1 = (n0+64 < NN) ? n0+64 : NN;
  if (n0 >= NN) return;
  const int t = threadIdx.x;
  float sum=0.f, mx=0.f;
  int curg = batch[n0];
  int segstart = n0;
  for (int n=n0; n<n1; ++n){
    const int g = batch[n];
    if (g != curg){
      atomicAdd(&pooled[curg*768+512+t], sum);
      atomicMax((unsigned int*)&pooled[curg*768+256+t], __float_as_uint(mx));
      if (t==0) atomicAdd(&gcnt[curg], n-segstart);
      sum=0.f; mx=0.f; curg=g; segstart=n;
    }
    float v = b2f(x3[(size_t)n*256+t]);
    sum += v; mx = fmaxf(mx, v);
  }
  atomicAdd(&pooled[curg*768+512+t], sum);
  atomicMax((unsigned int*)&pooled[curg*768+256+t], __float_as_uint(mx));
  if (t==0) atomicAdd(&gcnt[curg], n1-segstart);
}
__global__ __launch_bounds__(256) void k_pool_fin(float* __restrict__ pooled, const int* __restrict__ gcnt){
  int i = blockIdx.x*256 + threadIdx.x;
  if (i >= NG*256) return;
  int g = i>>8, c = i&255;
  float s = pooled[g*768+512+c];
  int cnt = gcnt[g];
  pooled[g*768+c] = s / (float)(cnt>1?cnt:1);
}

// ---------------- readout MLPs ----------------
__global__ __launch_bounds__(256) void k_gvec(const float* __restrict__ pooled, const u16* __restrict__ Wp,
                                              const u16* __restrict__ bp, float* __restrict__ gbuf){
  const int g = blockIdx.x, t = threadIdx.x;
  __shared__ float ps[768];
  for (int i=t;i<768;i+=256) ps[i] = pooled[g*768+i];
  __syncthreads();
  float acc = b2f(bp[t]);
  for (int k=0;k<768;k++) acc += ps[k]*b2f(Wp[k*256+t]);
  gbuf[g*256+t] = acc>0.f ? acc : 0.f;
}
__global__ __launch_bounds__(128) void k_heads(const float* __restrict__ gbuf,
    const u16* Wv1,const u16* bv1,const u16* Wv2,const u16* bv2,const u16* Wv3,const u16* bv3,
    const u16* Wt1,const u16* bt1,const u16* Wt2,const u16* bt2,const u16* Wt3,const u16* bt3,
    const u16* Wc1,const u16* bc1,const u16* Wc2,const u16* bc2,
    void* __restrict__ outp, const int* __restrict__ flag){
  const int g = blockIdx.x, t = threadIdx.x;
  const int f32o = *flag;
  u16* o16 = (u16*)outp;
  float* o32 = (float*)outp;
  __shared__ float gs[256], h1[128], h2[64];
  gs[t] = gbuf[g*256+t]; gs[t+128] = gbuf[g*256+t+128];
  __syncthreads();
  { float a = b2f(bv1[t]); for (int k=0;k<256;k++) a += gs[k]*b2f(Wv1[k*128+t]); h1[t] = a>0.f?a:0.f; }
  __syncthreads();
  if (t<64){ float a=b2f(bv2[t]); for(int k=0;k<128;k++) a += h1[k]*b2f(Wv2[k*64+t]); h2[t]=a>0.f?a:0.f; }
  __syncthreads();
  if (t<2){ float a=b2f(bv3[t]); for(int k=0;k<64;k++) a += h2[k]*b2f(Wv3[k*2+t]);
            if (f32o) o32[g*2+t]=a; else o16[g*2+t]=f2b(a); }
  __syncthreads();
  { float a = b2f(bt1[t]); for (int k=0;k<256;k++) a += gs[k]*b2f(Wt1[k*128+t]); h1[t] = a>0.f?a:0.f; }
  __syncthreads();
  if (t<64){ float a=b2f(bt2[t]); for(int k=0;k<128;k++) a += h1[k]*b2f(Wt2[k*64+t]); h2[t]=a>0.f?a:0.f; }
  __syncthreads();
  if (t<10){ float a=b2f(bt3[t]); for(int k=0;k<64;k++) a += h2[k]*b2f(Wt3[k*10+t]);
             if (f32o) o32[128 + g*10+t]=a; else o16[128 + g*10+t]=f2b(a); }
  __syncthreads();
  if (t<64){ float a=b2f(bc1[t]); for(int k=0;k<256;k++) a += gs[k]*b2f(Wc1[k*64+t]); h2[t]=a>0.f?a:0.f; }
  __syncthreads();
  if (t==0){
    float a=b2f(bc2[0]);
    for(int k=0;k<64;k++) a += h2[k]*b2f(Wc2[k]);
    float r = 1.f/(1.f+__expf(-a));
    if (f32o) o32[768+g]=r; else o16[768+g]=f2b(r);
  }
}

extern "C" void kernel_launch(void* const* d_in, const int* in_sizes, int n_in,
                              void* d_out, int out_size, void* d_ws, size_t ws_size,
                              hipStream_t stream){
  (void)in_sizes; (void)n_in; (void)out_size; (void)ws_size;
  const int* eidx = (const int*)d_in[1];
  const int* batch= (const int*)d_in[2];

  char* ws = (char*)d_ws;
  size_t off = 0;
  auto alloc = [&](size_t bytes) -> void* {
    void* p = ws + off;
    off += (bytes + 255) & ~(size_t)255;
    return p;
  };
  u16* bufA  = (u16*)alloc((size_t)NP*1024*2);
  u16* bufH  = (u16*)alloc((size_t)NP*1024*2);
  u16* W1t   = (u16*)alloc((size_t)1024*256*2);
  u16* W2t   = (u16*)alloc((size_t)1024*1024*2);
  u16* W3t   = (u16*)alloc((size_t)1024*1024*2);
  u16* WinT  = (u16*)alloc((size_t)256*64*2);
  // union region: Xp (used only before first k_soft) overlays wbuf+invs
  const size_t wbytes = ((size_t)(NE+NN)*8*4 + 255) & ~(size_t)255;
  const size_t ibytes = (size_t)NN*8*4;
  const size_t xbytes = (size_t)NP*64*2;
  char* un = (char*)alloc(wbytes + ibytes > xbytes ? wbytes + ibytes : xbytes);
  u16*   Xp   = (u16*)un;
  float* wbuf = (float*)un;
  float* invs = (float*)(un + wbytes);
  float* asb = (float*)alloc((size_t)NN*8*4);
  float* adb = (float*)alloc((size_t)NN*8*4);
  int* counts= (int*)alloc((size_t)NN*4);
  int* cursor= (int*)alloc((size_t)NN*4);
  int* indptr= (int*)alloc((size_t)(NN+1)*4);
  int* srcs  = (int*)alloc((size_t)(NE+NN)*4);
  float* pooled = (float*)alloc((size_t)NG*768*4);
  float* gbuf   = (float*)alloc((size_t)NG*256*4);
  int* gcnt  = (int*)alloc((size_t)NG*4);
  u16* cvt   = (u16*)alloc((size_t)320*1024*2);
  int* flag  = (int*)alloc(256);

  // conversion jobs for all small params (everything except x, Win, W1, W2, W3)
  CvtJobs jobs; int ji = 0; int cvtoff = 0; int cume = 0;
  auto addjob = [&](int idx, int n) -> u16* {
    jobs.src[ji] = d_in[idx]; jobs.n[ji] = n; jobs.dstoff[ji] = cvtoff;
    jobs.cum[ji] = cume; cume += n; ji++;
    u16* r = cvt + cvtoff; cvtoff = (cvtoff + n + 15) & ~15; return r;
  };
  u16* cb_in= addjob(4, 256);
  u16* cas1 = addjob(6, 1024);  u16* cad1 = addjob(7, 1024);
  u16* cb1  = addjob(8, 1024);  u16* cg1  = addjob(9, 1024);  u16* cbe1 = addjob(10, 1024);
  u16* cas2 = addjob(12, 1024); u16* cad2 = addjob(13, 1024);
  u16* cb2  = addjob(14, 1024); u16* cg2  = addjob(15, 1024); u16* cbe2 = addjob(16, 1024);
  u16* cas3 = addjob(18, 1024); u16* cad3 = addjob(19, 1024);
  u16* cb3  = addjob(20, 256);  u16* cg3  = addjob(21, 256);  u16* cbe3 = addjob(22, 256);
  u16* cWp  = addjob(23, 196608); u16* cbp = addjob(24, 256);
  u16* cWv1 = addjob(25, 32768);  u16* cbv1= addjob(26, 128);
  u16* cWv2 = addjob(27, 8192);   u16* cbv2= addjob(28, 64);
  u16* cWv3 = addjob(29, 128);    u16* cbv3= addjob(30, 2);
  u16* cWt1 = addjob(31, 32768);  u16* cbt1= addjob(32, 128);
  u16* cWt2 = addjob(33, 8192);   u16* cbt2= addjob(34, 64);
  u16* cWt3 = addjob(35, 640);    u16* cbt3= addjob(36, 10);
  u16* cWc1 = addjob(37, 16384);  u16* cbc1= addjob(38, 64);
  u16* cWc2 = addjob(39, 64);     u16* cbc2= addjob(40, 1);
  jobs.cum[ji] = cume; jobs.njobs = ji; jobs.total = cume;

  // dtype detection + conversions
  k_detect<<<1, 64, 0, stream>>>((const uint32_t*)d_in[3], flag);
  k_cvt<<<(cume+255)/256, 256, 0, stream>>>(jobs, flag, cvt);
  k_pad_x<<<(NP*64+255)/256, 256, 0, stream>>>(d_in[0], Xp, flag);
  k_pad_winT<<<(256*64+255)/256, 256, 0, stream>>>(d_in[3], WinT, flag);
  k_transpose<<<(256*1024+255)/256, 256, 0, stream>>>(d_in[5], W1t, 256, 1024, flag);
  k_transpose<<<(1024*1024+255)/256, 256, 0, stream>>>(d_in[11], W2t, 1024, 1024, flag);
  k_transpose<<<(1024*1024+255)/256, 256, 0, stream>>>(d_in[17], W3t, 1024, 1024, flag);

  // CSR build
  k_init_counts<<<(NN+255)/256, 256, 0, stream>>>(counts);
  k_count<<<(NE+255)/256, 256, 0, stream>>>(eidx, counts);
  k_scan<<<1, 1024, 0, stream>>>(counts, indptr, cursor);
  k_fill<<<(NE+NN+255)/256, 256, 0, stream>>>(eidx, cursor, srcs);

  // input transform: relu(x @ Win + b_in) -> bufA [NP,256]
  k_gemm_bt<64,true,1><<<dim3((NP/128)*2), 256, 0, stream>>>(Xp, WinT, bufA, 256, cb_in);

  // layer 1 (H=8, C=128)
  k_gemm256<256,4><<<dim3((NP/256)*4), 512, 0, stream>>>(bufA, W1t, bufH, 1024);
  k_alpha<8><<<(NN+3)/4, 256, 0, stream>>>(bufH, cas1, cad1, asb, adb);
  k_soft<8><<<(NN*8+255)/256, 256, 0, stream>>>(asb, adb, indptr, srcs, wbuf, invs);
  k_agg2<8,128,false><<<NP, 256, 0, stream>>>(bufH, wbuf, invs, indptr, srcs, cb1, cg1, cbe1, bufA);

  // layer 2 (H=8, C=128)
  k_gemm256<1024,4><<<dim3((NP/256)*4), 512, 0, stream>>>(bufA, W2t, bufH, 1024);
  k_alpha<8><<<(NN+3)/4, 256, 0, stream>>>(bufH, cas2, cad2, asb, adb);
  k_soft<8><<<(NN*8+255)/256, 256, 0, stream>>>(asb, adb, indptr, srcs, wbuf, invs);
  k_agg2<8,128,false><<<NP, 256, 0, stream>>>(bufH, wbuf, invs, indptr, srcs, cb2, cg2, cbe2, bufA);

  // layer 3 (H=4, C=256, mean over heads)
  k_gemm256<1024,4><<<dim3((NP/256)*4), 512, 0, stream>>>(bufA, W3t, bufH, 1024);
  k_alpha<4><<<(NN+3)/4, 256, 0, stream>>>(bufH, cas3, cad3, asb, adb);
  k_soft<4><<<(NN*4+255)/256, 256, 0, stream>>>(asb, adb, indptr, srcs, wbuf, invs);
  k_agg2<4,256,true><<<NP, 256, 0, stream>>>(bufH, wbuf, invs, indptr, srcs, cb3, cg3, cbe3, bufA);

  // pooling + readout
  k_pool_init<<<(NG*768+255)/256, 256, 0, stream>>>(pooled, gcnt);
  k_pool1<<<(NN+63)/64, 256, 0, stream>>>(bufA, batch, pooled, gcnt);
  k_pool_fin<<<(NG*256+255)/256, 256, 0, stream>>>(pooled, gcnt);
  k_gvec<<<NG, 256, 0, stream>>>(pooled, cWp, cbp, gbuf);
  k_heads<<<NG, 128, 0, stream>>>(gbuf, cWv1,cbv1,cWv2,cbv2,cWv3,cbv3,
                                  cWt1,cbt1,cWt2,cbt2,cWt3,cbt3, cWc1,cbc1,cWc2,cbc2,
                                  d_out, flag);
}